// Round 11
// baseline (293.353 us; speedup 1.0000x reference)
//
#include <hip/hip_runtime.h>
#include <hip/hip_bf16.h>

// ---- problem constants ----
#define BB      2
#define LSEQ    2048
#define DMODEL  1024
#define DSTATE  128
#define DCONV   4
#define HEADDIM 64
#define DINNER  2048      // EXP*DMODEL
#define NHEADS  32        // DINNER/HEADDIM
#define CONVD   2304      // DINNER + 2*DSTATE
#define DINP    4384      // 2*DINNER + 2*DSTATE + NHEADS
#define CHUNK   256
#define NCH     8         // LSEQ/CHUNK
#define NROWS   4096      // BB*LSEQ
#define EPSF    1e-5f
#define TPAD    264       // LDS transpose row pitch (ushort)

typedef __attribute__((ext_vector_type(8))) short bf16x8;
typedef __attribute__((ext_vector_type(4))) float f32x4;

#define ASYNC_COPY16(gptr, lptr) \
    __builtin_amdgcn_global_load_lds((const __attribute__((address_space(1))) void*)(gptr), \
                                     (__attribute__((address_space(3))) void*)(lptr), 16, 0, 0)

__device__ __forceinline__ ushort f2bf(float f) {
    __hip_bfloat16 h = __float2bfloat16(f);
    return *(ushort*)&h;
}
__device__ __forceinline__ float bf2f(ushort u) {
    return __uint_as_float(((unsigned)u) << 16);
}
// truncation (toward zero) float->bf16: 1 op, <=2^-8 rel err — hot paths only
__device__ __forceinline__ short tb(float f) { return (short)(__float_as_uint(f) >> 16); }

// XCD-aware bijective pid swizzle: consecutive tiles share one XCD's L2.
// [round-6 proven: gemm1 FETCH 77->35MB, dur 59->52.6us]
__device__ __forceinline__ int xcd_swizzle(int pid, int nwg) {
    return ((nwg & 7) == 0) ? (pid & 7) * (nwg >> 3) + (pid >> 3) : pid;
}

// ============================================================
// Prologue: wi cvt (padded to 4480 rows), wo cvt (pre-scaled by gnorm_w),
// rmsnorm->bf16, ssq zeroing.
// grid: [0,4480) wi | [4480,6528) wo | [6528,10624) rmsnorm | [10624,10640) ssq=0
// ============================================================
__global__ __launch_bounds__(256) void prologue_kernel(
    const float* __restrict__ x, const float* __restrict__ norm_w,
    const float* __restrict__ in_proj_w, const float* __restrict__ out_proj_w,
    const float* __restrict__ gnorm_w,
    ushort* __restrict__ xn_bf, ushort* __restrict__ wi_bf,
    ushort* __restrict__ wo_bf, float* __restrict__ ssq)
{
    int bid = blockIdx.x;
    if (bid < 4480) {                 // wi: 4480x1024 bf16, zero-pad rows >= 4384
        long i4 = ((long)bid * 256 + threadIdx.x) * 4;
        int n = (int)(i4 >> 10);
        long k = i4 & 1023;
        ushort4 o;
        if (n < DINP) {
            float4 v = *(const float4*)(in_proj_w + ((long)n << 10) + k);
            o.x = f2bf(v.x); o.y = f2bf(v.y); o.z = f2bf(v.z); o.w = f2bf(v.w);
        } else { o.x = o.y = o.z = o.w = 0; }
        *(ushort4*)(wi_bf + i4) = o;
    } else if (bid < 6528) {          // wo': 1024x2048 bf16, folded gnorm_w
        long i4 = ((long)(bid - 4480) * 256 + threadIdx.x) * 4;
        int k = (int)(i4 & 2047);
        float4 v = *(const float4*)(out_proj_w + i4);
        float4 g = *(const float4*)(gnorm_w + k);
        ushort4 o;
        o.x = f2bf(v.x * g.x); o.y = f2bf(v.y * g.y);
        o.z = f2bf(v.z * g.z); o.w = f2bf(v.w * g.w);
        *(ushort4*)(wo_bf + i4) = o;
    } else if (bid < 10624) {         // rmsnorm row -> bf16
        int row = bid - 6528;
        const float* xr = x + (long)row * DMODEL;
        float4 v = *(const float4*)(xr + threadIdx.x * 4);
        float ss = v.x*v.x + v.y*v.y + v.z*v.z + v.w*v.w;
        for (int off = 32; off; off >>= 1) ss += __shfl_down(ss, off, 64);
        __shared__ float red[4];
        if ((threadIdx.x & 63) == 0) red[threadIdx.x >> 6] = ss;
        __syncthreads();
        float tot = red[0] + red[1] + red[2] + red[3];
        float scale = rsqrtf(tot / (float)DMODEL + EPSF);
        float4 wv = *(const float4*)(norm_w + threadIdx.x * 4);
        ushort4 o;
        o.x = f2bf(v.x * scale * wv.x); o.y = f2bf(v.y * scale * wv.y);
        o.z = f2bf(v.z * scale * wv.z); o.w = f2bf(v.w * scale * wv.w);
        *(ushort4*)(xn_bf + (long)row * DMODEL + threadIdx.x * 4) = o;
    } else {                          // ssq = 0
        ssq[(bid - 10624) * 256 + threadIdx.x] = 0.f;
    }
}

// ============================================================
// Big bf16 MFMA NT GEMM: 128x128 tile, BK=64, 32 MFMA/K-step.
// [proven: 52.6us gemm1, 0 conflicts, FETCH 35MB w/ swizzle]
// ============================================================
__global__ __launch_bounds__(256, 3) void gemm_bf16_kernel(
    const ushort* __restrict__ A, int lda, long sA,
    const ushort* __restrict__ W, int ldw, long sW,
    void* __restrict__ Cout, int ldc, long sC, int c_bf16,
    const float* __restrict__ resid, const float* __restrict__ rowscale,
    int mtiles, int ntiles, int N, int K)
{
    __shared__ __align__(16) char smem[34816];
    ushort* As = (ushort*)smem;          // 128*64 ushort = 16 KB
    ushort* Bs = As + 128 * 64;          // 128*64 ushort = 16 KB
    ushort* tu = (ushort*)smem;          // epilogue bf16 tile [128][136] = 34 KB
    float*  tf = (float*)smem;           // epilogue fp32 tile [64][132] = 33 KB

    const int t = threadIdx.x;
    const int lane = t & 63;
    const int w = t >> 6;
    const int wm = w & 1, wn = w >> 1;
    const int lm = lane & 15, quad = lane >> 4;

    int pid = xcd_swizzle(blockIdx.x, gridDim.x);
    const int GM = 8;
    int width = GM * ntiles;
    int group = pid / width;
    int first_m = group * GM;
    int gsz = mtiles - first_m; if (gsz > GM) gsz = GM;
    int mt = first_m + (pid % width) % gsz;
    int nt = (pid % width) / gsz;
    const int m0 = mt * 128, n0 = nt * 128;

    A += (long)blockIdx.z * sA;
    W += (long)blockIdx.z * sW;

    const ushort* ga[4]; const ushort* gw[4];
#pragma unroll
    for (int i = 0; i < 4; ++i) {
        int s = i * 256 + t;
        int row = s >> 3;
        int kseg = (s & 7) ^ (row & 7);
        ga[i] = A + (long)(m0 + row) * lda + kseg * 8;
        gw[i] = W + (long)(n0 + row) * ldw + kseg * 8;
    }

    f32x4 acc[4][4];
    f32x4 zero4 = {0.f, 0.f, 0.f, 0.f};
#pragma unroll
    for (int i = 0; i < 4; ++i)
#pragma unroll
        for (int j = 0; j < 4; ++j) acc[i][j] = zero4;

    int arow8[4], arow7[4], brow8[4], brow7[4];
#pragma unroll
    for (int i = 0; i < 4; ++i) {
        int ar = wm * 64 + i * 16 + lm;
        arow8[i] = ar * 8; arow7[i] = ar & 7;
        int br = wn * 64 + i * 16 + lm;
        brow8[i] = br * 8; brow7[i] = br & 7;
    }

    for (int k0 = 0; k0 < K; k0 += 64) {
#pragma unroll
        for (int i = 0; i < 4; ++i) {
            ASYNC_COPY16(ga[i], &As[(i * 256 + w * 64) * 8]);
            ga[i] += 64;
        }
#pragma unroll
        for (int i = 0; i < 4; ++i) {
            ASYNC_COPY16(gw[i], &Bs[(i * 256 + w * 64) * 8]);
            gw[i] += 64;
        }
        __syncthreads();
#pragma unroll
        for (int ks = 0; ks < 2; ++ks) {
            bf16x8 af[4], bfr[4];
#pragma unroll
            for (int i = 0; i < 4; ++i)
                af[i]  = *(const bf16x8*)&As[(arow8[i] + ((ks * 4 + quad) ^ arow7[i])) * 8];
#pragma unroll
            for (int i = 0; i < 4; ++i)
                bfr[i] = *(const bf16x8*)&Bs[(brow8[i] + ((ks * 4 + quad) ^ brow7[i])) * 8];
#pragma unroll
            for (int im = 0; im < 4; ++im)
#pragma unroll
                for (int in = 0; in < 4; ++in)
                    acc[im][in] = __builtin_amdgcn_mfma_f32_16x16x32_bf16(
                        af[im], bfr[in], acc[im][in], 0, 0, 0);
        }
        __syncthreads();
    }

    // ---- epilogue: LDS bounce -> coalesced full-line stores ----
    if (c_bf16) {
        ushort* C = (ushort*)Cout + (long)blockIdx.z * sC;
#pragma unroll
        for (int mi = 0; mi < 4; ++mi)
#pragma unroll
            for (int ni = 0; ni < 4; ++ni) {
                int c = wn * 64 + ni * 16 + lm;
#pragma unroll
                for (int i = 0; i < 4; ++i) {
                    int r = wm * 64 + mi * 16 + quad * 4 + i;
                    tu[r * 136 + c] = f2bf(acc[mi][ni][i]);
                }
            }
        __syncthreads();
        int r = t >> 1, cb = (t & 1) * 64;
        long rowbase = (long)(m0 + r) * ldc + n0 + cb;
#pragma unroll
        for (int q = 0; q < 8; ++q) {
            int gcol = n0 + cb + q * 8;
            if (gcol < N)
                *(bf16x8*)(C + rowbase + q * 8) =
                    *(const bf16x8*)&tu[r * 136 + cb + q * 8];
        }
    } else {
        float* C = (float*)Cout + (long)blockIdx.z * sC;
#pragma unroll
        for (int p = 0; p < 2; ++p) {
            if (wm == p) {
#pragma unroll
                for (int mi = 0; mi < 4; ++mi)
#pragma unroll
                    for (int i = 0; i < 4; ++i) {
                        int r = mi * 16 + quad * 4 + i;
                        float s = 1.f;
                        if (rowscale)
                            s = rsqrtf(rowscale[m0 + p * 64 + r] * (1.f / (float)DINNER) + EPSF);
#pragma unroll
                        for (int ni = 0; ni < 4; ++ni) {
                            int c = wn * 64 + ni * 16 + lm;
                            tf[r * 132 + c] = acc[mi][ni][i] * s;
                        }
                    }
            }
            __syncthreads();
            int r2 = t >> 2, cb = (t & 3) * 32;
            long gbase = (long)(m0 + p * 64 + r2) * ldc + n0 + cb;
#pragma unroll
            for (int q = 0; q < 8; ++q) {
                float4 v = *(const float4*)&tf[r2 * 132 + cb + q * 4];
                if (resid) {
                    float4 rv = *(const float4*)(resid + gbase + q * 4);
                    v.x += rv.x; v.y += rv.y; v.z += rv.z; v.w += rv.w;
                }
                *(float4*)(C + gbase + q * 4) = v;
            }
            __syncthreads();
        }
    }
}

// ============================================================
// Small bf16 MFMA NT GEMM: 128x64 tile, 16 MFMA/K-step — used for
// gemm4 (bf16-out batched tiny GEMM).
// ============================================================
__global__ __launch_bounds__(256, 4) void gemm_bf16_s_kernel(
    const ushort* __restrict__ A, int lda, long sA,
    const ushort* __restrict__ W, int ldw, long sW,
    void* __restrict__ Cout, int ldc, long sC, int c_bf16,
    const float* __restrict__ resid, const float* __restrict__ rowscale,
    int mtiles, int ntiles, int N, int K)
{
    __shared__ __align__(16) char smem[24576];
    ushort* As = (ushort*)smem;          // 128*64 ushort = 16 KB
    ushort* Bs = As + 128 * 64;          //  64*64 ushort =  8 KB
    ushort* tu = (ushort*)smem;          // epilogue bf16 tile [128][72]
    float*  tf = (float*)smem;           // epilogue fp32 tile [64][68]

    const int t = threadIdx.x;
    const int lane = t & 63;
    const int w = t >> 6;
    const int wm = w & 1, wn = w >> 1;
    const int lm = lane & 15, quad = lane >> 4;

    int pid = xcd_swizzle(blockIdx.x, gridDim.x);
    const int GM = 8;
    int width = GM * ntiles;
    int group = pid / width;
    int first_m = group * GM;
    int gsz = mtiles - first_m; if (gsz > GM) gsz = GM;
    int mt = first_m + (pid % width) % gsz;
    int nt = (pid % width) / gsz;
    const int m0 = mt * 128, n0 = nt * 64;

    A += (long)blockIdx.z * sA;
    W += (long)blockIdx.z * sW;

    const ushort* ga[4]; const ushort* gw[2];
#pragma unroll
    for (int i = 0; i < 4; ++i) {
        int s = i * 256 + t;
        int row = s >> 3;
        int kseg = (s & 7) ^ (row & 7);
        ga[i] = A + (long)(m0 + row) * lda + kseg * 8;
    }
#pragma unroll
    for (int i = 0; i < 2; ++i) {
        int s = i * 256 + t;
        int row = s >> 3;
        int kseg = (s & 7) ^ (row & 7);
        gw[i] = W + (long)(n0 + row) * ldw + kseg * 8;
    }

    f32x4 acc[4][2];
    f32x4 zero4 = {0.f, 0.f, 0.f, 0.f};
#pragma unroll
    for (int i = 0; i < 4; ++i) { acc[i][0] = zero4; acc[i][1] = zero4; }

    int arow8[4], arow7[4], brow8[2], brow7[2];
#pragma unroll
    for (int i = 0; i < 4; ++i) {
        int ar = wm * 64 + i * 16 + lm;
        arow8[i] = ar * 8; arow7[i] = ar & 7;
    }
#pragma unroll
    for (int i = 0; i < 2; ++i) {
        int br = wn * 32 + i * 16 + lm;
        brow8[i] = br * 8; brow7[i] = br & 7;
    }

    for (int k0 = 0; k0 < K; k0 += 64) {
#pragma unroll
        for (int i = 0; i < 4; ++i) {
            ASYNC_COPY16(ga[i], &As[(i * 256 + w * 64) * 8]);
            ga[i] += 64;
        }
#pragma unroll
        for (int i = 0; i < 2; ++i) {
            ASYNC_COPY16(gw[i], &Bs[(i * 256 + w * 64) * 8]);
            gw[i] += 64;
        }
        __syncthreads();
#pragma unroll
        for (int ks = 0; ks < 2; ++ks) {
            bf16x8 af[4], bfr[2];
#pragma unroll
            for (int i = 0; i < 4; ++i)
                af[i]  = *(const bf16x8*)&As[(arow8[i] + ((ks * 4 + quad) ^ arow7[i])) * 8];
#pragma unroll
            for (int i = 0; i < 2; ++i)
                bfr[i] = *(const bf16x8*)&Bs[(brow8[i] + ((ks * 4 + quad) ^ brow7[i])) * 8];
#pragma unroll
            for (int im = 0; im < 4; ++im)
#pragma unroll
                for (int in = 0; in < 2; ++in)
                    acc[im][in] = __builtin_amdgcn_mfma_f32_16x16x32_bf16(
                        af[im], bfr[in], acc[im][in], 0, 0, 0);
        }
        __syncthreads();
    }

    // ---- epilogue: LDS bounce -> coalesced full-line stores ----
    if (c_bf16) {
        ushort* C = (ushort*)Cout + (long)blockIdx.z * sC;
#pragma unroll
        for (int mi = 0; mi < 4; ++mi)
#pragma unroll
            for (int ni = 0; ni < 2; ++ni) {
                int c = wn * 32 + ni * 16 + lm;
#pragma unroll
                for (int i = 0; i < 4; ++i) {
                    int r = wm * 64 + mi * 16 + quad * 4 + i;
                    tu[r * 72 + c] = f2bf(acc[mi][ni][i]);
                }
            }
        __syncthreads();
        int r = t >> 1, cb = (t & 1) * 32;
        long rowbase = (long)(m0 + r) * ldc + n0 + cb;
#pragma unroll
        for (int q = 0; q < 4; ++q) {
            int gcol = n0 + cb + q * 8;
            if (gcol < N)
                *(bf16x8*)(C + rowbase + q * 8) =
                    *(const bf16x8*)&tu[r * 72 + cb + q * 8];
        }
    } else {
        float* C = (float*)Cout + (long)blockIdx.z * sC;
#pragma unroll
        for (int p = 0; p < 2; ++p) {
            if (wm == p) {
#pragma unroll
                for (int mi = 0; mi < 4; ++mi)
#pragma unroll
                    for (int i = 0; i < 4; ++i) {
                        int r = mi * 16 + quad * 4 + i;
                        float s = 1.f;
                        if (rowscale)
                            s = rsqrtf(rowscale[m0 + p * 64 + r] * (1.f / (float)DINNER) + EPSF);
#pragma unroll
                        for (int ni = 0; ni < 2; ++ni) {
                            int c = wn * 32 + ni * 16 + lm;
                            tf[r * 68 + c] = acc[mi][ni][i] * s;
                        }
                    }
            }
            __syncthreads();
            int r2 = t >> 2, cb = (t & 3) * 16;
            long gbase = (long)(m0 + p * 64 + r2) * ldc + n0 + cb;
#pragma unroll
            for (int q = 0; q < 4; ++q) {
                float4 v = *(const float4*)&tf[r2 * 68 + cb + q * 4];
                if (resid) {
                    float4 rv = *(const float4*)(resid + gbase + q * 4);
                    v.x += rv.x; v.y += rv.y; v.z += rv.z; v.w += rv.w;
                }
                *(float4*)(C + gbase + q * 4) = v;
            }
            __syncthreads();
        }
    }
}

// ============================================================
// 64x64-tile bf16 MFMA NT GEMM for gemm8 (latency-bound K=2048):
// 1024 blocks -> 4 resident/CU. [round-10 proven: gemm8 out of top-5]
// ============================================================
__global__ __launch_bounds__(256, 4) void gemm64_kernel(
    const ushort* __restrict__ A, int lda,
    const ushort* __restrict__ W, int ldw,
    float* __restrict__ Cout, int ldc,
    const float* __restrict__ resid, const float* __restrict__ rowscale,
    int mtiles, int ntiles, int K)
{
    __shared__ __align__(16) char smem[17408];
    ushort* As = (ushort*)smem;          // 64*64 ushort = 8 KB
    ushort* Bs = As + 64 * 64;           // 8 KB
    float*  tf = (float*)smem;           // epilogue fp32 tile [64][68] = 17408 B

    const int t = threadIdx.x;
    const int lane = t & 63;
    const int w = t >> 6;
    const int wm = w & 1, wn = w >> 1;
    const int lm = lane & 15, quad = lane >> 4;

    int pid = xcd_swizzle(blockIdx.x, gridDim.x);
    const int GM = 8;
    int width = GM * ntiles;
    int group = pid / width;
    int first_m = group * GM;
    int gsz = mtiles - first_m; if (gsz > GM) gsz = GM;
    int mt = first_m + (pid % width) % gsz;
    int nt = (pid % width) / gsz;
    const int m0 = mt * 64, n0 = nt * 64;

    const ushort* ga[2]; const ushort* gw[2];
#pragma unroll
    for (int i = 0; i < 2; ++i) {
        int s = i * 256 + t;
        int row = s >> 3;
        int kseg = (s & 7) ^ (row & 7);
        ga[i] = A + (long)(m0 + row) * lda + kseg * 8;
        gw[i] = W + (long)(n0 + row) * ldw + kseg * 8;
    }

    f32x4 acc[2][2];
    f32x4 zero4 = {0.f, 0.f, 0.f, 0.f};
    acc[0][0] = zero4; acc[0][1] = zero4;
    acc[1][0] = zero4; acc[1][1] = zero4;

    int arow8[2], arow7[2], brow8[2], brow7[2];
#pragma unroll
    for (int i = 0; i < 2; ++i) {
        int ar = wm * 32 + i * 16 + lm;
        arow8[i] = ar * 8; arow7[i] = ar & 7;
        int br = wn * 32 + i * 16 + lm;
        brow8[i] = br * 8; brow7[i] = br & 7;
    }

    for (int k0 = 0; k0 < K; k0 += 64) {
#pragma unroll
        for (int i = 0; i < 2; ++i) {
            ASYNC_COPY16(ga[i], &As[(i * 256 + w * 64) * 8]);
            ga[i] += 64;
            ASYNC_COPY16(gw[i], &Bs[(i * 256 + w * 64) * 8]);
            gw[i] += 64;
        }
        __syncthreads();
#pragma unroll
        for (int ks = 0; ks < 2; ++ks) {
            bf16x8 af[2], bfr[2];
#pragma unroll
            for (int i = 0; i < 2; ++i) {
                af[i]  = *(const bf16x8*)&As[(arow8[i] + ((ks * 4 + quad) ^ arow7[i])) * 8];
                bfr[i] = *(const bf16x8*)&Bs[(brow8[i] + ((ks * 4 + quad) ^ brow7[i])) * 8];
            }
#pragma unroll
            for (int im = 0; im < 2; ++im)
#pragma unroll
                for (int in = 0; in < 2; ++in)
                    acc[im][in] = __builtin_amdgcn_mfma_f32_16x16x32_bf16(
                        af[im], bfr[in], acc[im][in], 0, 0, 0);
        }
        __syncthreads();
    }

    // ---- epilogue: rowscale + resid, LDS bounce -> coalesced fp32 stores ----
#pragma unroll
    for (int mi = 0; mi < 2; ++mi)
#pragma unroll
        for (int i = 0; i < 4; ++i) {
            int r = wm * 32 + mi * 16 + quad * 4 + i;
            float s = rsqrtf(rowscale[m0 + r] * (1.f / (float)DINNER) + EPSF);
#pragma unroll
            for (int ni = 0; ni < 2; ++ni) {
                int c = wn * 32 + ni * 16 + lm;
                tf[r * 68 + c] = acc[mi][ni][i] * s;
            }
        }
    __syncthreads();
    int r2 = t >> 2, cb = (t & 3) * 16;
    long gbase = (long)(m0 + r2) * ldc + n0 + cb;
#pragma unroll
    for (int q = 0; q < 4; ++q) {
        float4 v = *(const float4*)&tf[r2 * 68 + cb + q * 4];
        float4 rv = *(const float4*)(resid + gbase + q * 4);
        v.x += rv.x; v.y += rv.y; v.z += rv.z; v.w += rv.w;
        *(float4*)(Cout + gbase + q * 4) = v;
    }
}

// ============================================================
// Merged conv+SiLU + dt-softplus/cumsum.
// Main conv: per-row layout (ch 0..2047, 8 ch/thread); 256-ch tail
// in 512 dedicated blocks (8 rows x 32 lanes).
// grid: [0,4096) conv main | [4096,4608) conv tail | [4608,5120) acs
// ============================================================
__device__ __forceinline__ void conv8_row(
    const ushort* __restrict__ zx, const float* __restrict__ cw,
    const float* __restrict__ cb, ushort* __restrict__ xBC_bf,
    int row, int l, int c)
{
    float4 cwv[8];
#pragma unroll
    for (int j = 0; j < 8; ++j) cwv[j] = *(const float4*)(cw + (c + j) * 4);
    float acc[8];
    {
        float4 b0 = *(const float4*)(cb + c);
        float4 b1 = *(const float4*)(cb + c + 4);
        acc[0] = b0.x; acc[1] = b0.y; acc[2] = b0.z; acc[3] = b0.w;
        acc[4] = b1.x; acc[5] = b1.y; acc[6] = b1.z; acc[7] = b1.w;
    }
#pragma unroll
    for (int k = 0; k < DCONV; ++k) {
        int ls = l + k - (DCONV - 1);
        if (ls >= 0) {
            const ushort* zr = zx + (long)(row + k - (DCONV - 1)) * DINP + DINNER + c;
            ushort4 a = *(const ushort4*)zr;
            ushort4 b = *(const ushort4*)(zr + 4);
            acc[0] += bf2f(a.x) * ((const float*)&cwv[0])[k];
            acc[1] += bf2f(a.y) * ((const float*)&cwv[1])[k];
            acc[2] += bf2f(a.z) * ((const float*)&cwv[2])[k];
            acc[3] += bf2f(a.w) * ((const float*)&cwv[3])[k];
            acc[4] += bf2f(b.x) * ((const float*)&cwv[4])[k];
            acc[5] += bf2f(b.y) * ((const float*)&cwv[5])[k];
            acc[6] += bf2f(b.z) * ((const float*)&cwv[6])[k];
            acc[7] += bf2f(b.w) * ((const float*)&cwv[7])[k];
        }
    }
    ushort o[8];
#pragma unroll
    for (int j = 0; j < 8; ++j)
        o[j] = f2bf(acc[j] / (1.f + __expf(-acc[j])));
    ushort* dst = xBC_bf + (long)row * CONVD + c;
    *(ushort4*)dst = *(ushort4*)&o[0];
    *(ushort4*)(dst + 4) = *(ushort4*)&o[4];
}

__global__ __launch_bounds__(256) void conv_acs_kernel(
    const ushort* __restrict__ zx, const float* __restrict__ cw,
    const float* __restrict__ cb, ushort* __restrict__ xBC_bf,
    const float* __restrict__ dt_bias, const float* __restrict__ A_log,
    float* __restrict__ dtv, float* __restrict__ Acs)
{
    int bid = blockIdx.x;
    int t = threadIdx.x;
    if (bid < NROWS) {
        // ---- conv main: ch 0..2047, one row per block ----
        int row = bid;
        int l = row & (LSEQ - 1);
        conv8_row(zx, cw, cb, xBC_bf, row, l, t * 8);
    } else if (bid < NROWS + 512) {
        // ---- conv tail: ch 2048..2303, 8 rows per block ----
        int row = (bid - NROWS) * 8 + (t >> 5);
        int c = 2048 + (t & 31) * 8;
        int l = row & (LSEQ - 1);
        conv8_row(zx, cw, cb, xBC_bf, row, l, c);
    } else {
        // ---- dt softplus + per-chunk cumsum ----
        __shared__ float buf[2 * CHUNK];
        int idx = bid - (NROWS + 512);
        int bc = idx >> 5, h = idx & 31;
        int l = t;
        int row = bc * CHUNK + l;
        float v = bf2f(zx[(long)row * DINP + (DINP - NHEADS) + h]) + dt_bias[h];
        float d = (v > 20.f) ? v : log1pf(__expf(v));
        dtv[row * NHEADS + h] = d;
        float a = -d * __expf(A_log[h]);
        buf[l] = a; __syncthreads();
        int src = 0;
        for (int off = 1; off < CHUNK; off <<= 1) {
            float vv = buf[src * CHUNK + l];
            if (l >= off) vv += buf[src * CHUNK + l - off];
            buf[(src ^ 1) * CHUNK + l] = vv;
            __syncthreads();
            src ^= 1;
        }
        Acs[(bc * NHEADS + h) * CHUNK + l] = buf[src * CHUNK + l];
    }
}

// ============================================================
// Bt[bc][n][l] = B[l][n] (K-contiguous operand, shared by all heads)
// ============================================================
__global__ __launch_bounds__(256) void prep_b_kernel(
    const ushort* __restrict__ xBC_bf, ushort* __restrict__ Bt)
{
    int bc = blockIdx.x, half = blockIdx.y;
    int t = threadIdx.x;
    int row0 = bc * CHUNK;
    __shared__ ushort tB[64 * TPAD];
    int src_c0 = DINNER + half * 64;
    for (int iter = 0; iter < 8; ++iter) {
        int l = iter * 32 + (t >> 3);
        int cc = (t & 7) * 8;
        ushort u[8];
        *(ushort4*)&u[0] = *(const ushort4*)(xBC_bf + (long)(row0 + l) * CONVD + src_c0 + cc);
        *(ushort4*)&u[4] = *(const ushort4*)(xBC_bf + (long)(row0 + l) * CONVD + src_c0 + cc + 4);
#pragma unroll
        for (int j = 0; j < 8; ++j) tB[(cc + j) * TPAD + l] = u[j];
    }
    __syncthreads();
    int r = t >> 2, seg = (t & 3) * 64;
    ushort* dst = Bt + ((long)bc * DSTATE + half * 64 + r) * CHUNK + seg;
    const ushort* s1 = &tB[r * TPAD + seg];
#pragma unroll
    for (int q = 0; q < 16; ++q)
        *(ushort4*)(dst + q * 4) = *(const ushort4*)(s1 + q * 4);
}

// ============================================================
// Chunk state via MFMA with in-LDS X transpose:
//   S_t[p][n] = sum_l exp(T-acs_l)*dt_l*X[l,p] * Bt[n][l]  -> bf16
// ============================================================
__global__ __launch_bounds__(256) void chunk_state_mfma_kernel(
    const ushort* __restrict__ xBC_bf, const ushort* __restrict__ Bt,
    const float* __restrict__ dtv, const float* __restrict__ acs,
    ushort* __restrict__ state)
{
    int bc = blockIdx.x, h = blockIdx.y;
    int t = threadIdx.x, lane = t & 63, w = t >> 6;
    int lm = lane & 15, quad = lane >> 4;
    int row0 = bc * CHUNK;
    __shared__ ushort xt[64 * TPAD];
    __shared__ float cl[CHUNK];
    {
        float a = acs[(bc * NHEADS + h) * CHUNK + t];
        float T = acs[(bc * NHEADS + h) * CHUNK + CHUNK - 1];
        cl[t] = __expf(T - a) * dtv[(row0 + t) * NHEADS + h];
    }
    __syncthreads();
    for (int iter = 0; iter < 8; ++iter) {
        int l = iter * 32 + (t >> 3);
        int cc = (t & 7) * 8;
        ushort u[8];
        *(ushort4*)&u[0] = *(const ushort4*)(xBC_bf + (long)(row0 + l) * CONVD + h * HEADDIM + cc);
        *(ushort4*)&u[4] = *(const ushort4*)(xBC_bf + (long)(row0 + l) * CONVD + h * HEADDIM + cc + 4);
        float sc = cl[l];
#pragma unroll
        for (int j = 0; j < 8; ++j)
            xt[(cc + j) * TPAD + l] = (ushort)tb(bf2f(u[j]) * sc);
    }
    __syncthreads();

    const ushort* Bb = Bt + (long)bc * DSTATE * CHUNK;
    f32x4 acc[4][2];
    f32x4 zero4 = {0.f, 0.f, 0.f, 0.f};
#pragma unroll
    for (int i = 0; i < 4; ++i) { acc[i][0] = zero4; acc[i][1] = zero4; }

    for (int kt = 0; kt < 8; ++kt) {
        int k = kt * 32 + quad * 8;
        bf16x8 af[4], bfr[2];
#pragma unroll
        for (int mi = 0; mi < 4; ++mi)
            af[mi] = *(const bf16x8*)&xt[(mi * 16 + lm) * TPAD + k];
#pragma unroll
        for (int nj = 0; nj < 2; ++nj)
            bfr[nj] = *(const bf16x8*)(Bb + (long)(w * 32 + nj * 16 + lm) * CHUNK + k);
#pragma unroll
        for (int mi = 0; mi < 4; ++mi)
#pragma unroll
            for (int nj = 0; nj < 2; ++nj)
                acc[mi][nj] = __builtin_amdgcn_mfma_f32_16x16x32_bf16(
                    af[mi], bfr[nj], acc[mi][nj], 0, 0, 0);
    }
    ushort* sp = state + (long)(bc * NHEADS + h) * (DSTATE * HEADDIM);
#pragma unroll
    for (int mi = 0; mi < 4; ++mi)
#pragma unroll
        for (int nj = 0; nj < 2; ++nj) {
            int n = w * 32 + nj * 16 + lm;
#pragma unroll
            for (int i = 0; i < 4; ++i) {
                int p = mi * 16 + quad * 4 + i;
                sp[p * DSTATE + n] = f2bf(acc[mi][nj][i]);
            }
        }
}

// ============================================================
// Inter-chunk scan (in place on bf16 states, fp32 accumulator)
// ============================================================
__global__ __launch_bounds__(256) void state_scan_kernel(
    ushort* __restrict__ state, const float* __restrict__ Acs)
{
    long flat = (long)blockIdx.x * 256 + threadIdx.x;
    int e = (int)(flat & 8191);
    int bh = (int)(flat >> 13);
    int b = bh >> 5, h = bh & 31;
    float S = 0.f;
    for (int c = 0; c < NCH; ++c) {
        int bc = b * NCH + c;
        long idx = ((long)(bc * NHEADS + h)) * 8192 + e;
        float T = Acs[(bc * NHEADS + h) * CHUNK + CHUNK - 1];
        float tmp = bf2f(state[idx]);
        state[idx] = f2bf(S);
        S = S * __expf(T) + tmp;
    }
}

// ============================================================
// SSD Y via MFMA, row-split for occupancy: blockIdx.z in {0,1} owns
// 128 of 256 chunk rows (balanced: rb[mj] = (2z+mj)*64 + w*16).
// Grid 512 -> 1024 blocks (4/CU); acc [2][4] halves reg pressure.
// z=0 transposes only cols 0..127 (causal reach).
// ============================================================
__global__ __launch_bounds__(256) void ssd_y_mfma_kernel(
    const ushort* __restrict__ xBC_bf, const ushort* __restrict__ G2b,
    const float* __restrict__ acs, const ushort* __restrict__ state,
    const ushort* __restrict__ zxb, const float* __restrict__ dtv,
    const float* __restrict__ Dh, ushort* __restrict__ ybf,
    float* __restrict__ ssq)
{
    int bc = blockIdx.x, h = blockIdx.y, z = blockIdx.z;
    int t = threadIdx.x, lane = t & 63, w = t >> 6;
    int lm = lane & 15, quad = lane >> 4;
    int row0 = bc * CHUNK;
    __shared__ ushort xt[64 * TPAD];
    __shared__ float acs_s[CHUNK];
    __shared__ float dl[CHUNK];
    acs_s[t] = acs[(bc * NHEADS + h) * CHUNK + t];
    dl[t] = dtv[(row0 + t) * NHEADS + h];
    __syncthreads();
    // transpose X chunk (dt-scaled) into LDS [p][l]; z=0 needs cols<128 only
    int niter = z ? 8 : 4;
    for (int iter = 0; iter < niter; ++iter) {
        int l = iter * 32 + (t >> 3);
        int cc = (t & 7) * 8;
        ushort u[8];
        *(ushort4*)&u[0] = *(const ushort4*)(xBC_bf + (long)(row0 + l) * CONVD + h * HEADDIM + cc);
        *(ushort4*)&u[4] = *(const ushort4*)(xBC_bf + (long)(row0 + l) * CONVD + h * HEADDIM + cc + 4);
        float sd = dl[l];
#pragma unroll
        for (int j = 0; j < 8; ++j)
            xt[(cc + j) * TPAD + l] = (ushort)tb(bf2f(u[j]) * sd);
    }
    __syncthreads();

    // rows owned by this block: rb[mj] = (2z+mj)*64 + w*16, mj<2
    int rb[2];
    float acs_l[2], eAl[2];
#pragma unroll
    for (int mj = 0; mj < 2; ++mj) {
        rb[mj] = (z * 2 + mj) * 64 + w * 16;
        acs_l[mj] = acs_s[rb[mj] + lm];
        eAl[mj] = __expf(acs_l[mj]);
    }
    f32x4 acc[2][4];
    f32x4 zero4 = {0.f, 0.f, 0.f, 0.f};
#pragma unroll
    for (int i = 0; i < 2; ++i)
#pragma unroll
        for (int j = 0; j < 4; ++j) acc[i][j] = zero4;

    const ushort* g2 = G2b + (long)bc * (CHUNK * CHUNK);

    // ---- phase A: diagonal (causal), factored exps ----
    int ksmax = ((z * 2 + 1) * 64 + w * 16 + 15) >> 5;
    for (int ks = 0; ks <= ksmax; ++ks) {
        int sq = ks * 32 + quad * 8;
        bf16x8 bfr[4];
#pragma unroll
        for (int ni = 0; ni < 4; ++ni)
            bfr[ni] = *(const bf16x8*)&xt[(ni * 16 + lm) * TPAD + sq];
        float base = acs_s[sq];
        float e8[8];
        e8[0] = 1.f;
#pragma unroll
        for (int j = 1; j < 8; ++j)
            e8[j] = __expf(fminf(base - acs_s[sq + j], 80.f));
#pragma unroll
        for (int mj = 0; mj < 2; ++mj) {
            int lmin = rb[mj];
            if (ks * 32 > lmin + 15) continue;
            int lv = lmin + lm;
            float em = __expf(fminf(acs_l[mj] - base, 0.f));
            bf16x8 g8 = *(const bf16x8*)(g2 + (long)lv * CHUNK + sq);
            bf16x8 af;
#pragma unroll
            for (int j = 0; j < 8; ++j) {
                float v = bf2f((ushort)g8[j]) * (em * e8[j]);
                af[j] = (sq + j > lv) ? (short)0 : tb(v);
            }
#pragma unroll
            for (int ni = 0; ni < 4; ++ni)
                acc[mj][ni] = __builtin_amdgcn_mfma_f32_16x16x32_bf16(
                    af, bfr[ni], acc[mj][ni], 0, 0, 0);
        }
    }

    // ---- phase B: off-diagonal (C*eAl @ S^T), bf16 state loads ----
    const ushort* sp = state + (long)(bc * NHEADS + h) * (DSTATE * HEADDIM);
    const ushort* Cb = xBC_bf + (long)row0 * CONVD + DINNER + DSTATE;
    for (int kt = 0; kt < 4; ++kt) {
        int n0 = kt * 32 + quad * 8;
        bf16x8 bfr[4];
#pragma unroll
        for (int ni = 0; ni < 4; ++ni)
            bfr[ni] = *(const bf16x8*)(sp + (long)(ni * 16 + lm) * DSTATE + n0);
#pragma unroll
        for (int mj = 0; mj < 2; ++mj) {
            int lv = rb[mj] + lm;
            bf16x8 cu = *(const bf16x8*)(Cb + (long)lv * CONVD + n0);
            bf16x8 ce;
            float e = eAl[mj];
#pragma unroll
            for (int j = 0; j < 8; ++j) ce[j] = tb(bf2f((ushort)cu[j]) * e);
#pragma unroll
            for (int ni = 0; ni < 4; ++ni)
                acc[mj][ni] = __builtin_amdgcn_mfma_f32_16x16x32_bf16(
                    ce, bfr[ni], acc[mj][ni], 0, 0, 0);
        }
    }

    // ---- epilogue: +D*xh, silu(z) gate, bf16 store + ssq ----
    float Dv = Dh[h];
#pragma unroll
    for (int mj = 0; mj < 2; ++mj)
#pragma unroll
        for (int i = 0; i < 4; ++i) {
            int l = rb[mj] + quad * 4 + i;
            long row = row0 + l;
            float ps = 0.f;
#pragma unroll
            for (int ni = 0; ni < 4; ++ni) {
                int p = ni * 16 + lm;
                float xh = bf2f(xBC_bf[row * CONVD + h * HEADDIM + p]);
                float zz = bf2f(zxb[row * DINP + h * HEADDIM + p]);
                float o = (acc[mj][ni][i] + Dv * xh) * (zz / (1.f + __expf(-zz)));
                ps += o * o;
                ybf[row * DINNER + h * HEADDIM + p] = f2bf(o);
            }
#pragma unroll
            for (int m = 1; m < 16; m <<= 1) ps += __shfl_xor(ps, m, 64);
            if (lm == 0) atomicAdd(&ssq[row], ps);
        }
}

// ============================================================
// launch
// ============================================================
extern "C" void kernel_launch(void* const* d_in, const int* in_sizes, int n_in,
                              void* d_out, int out_size, void* d_ws, size_t ws_size,
                              hipStream_t stream)
{
    (void)in_sizes; (void)n_in; (void)out_size; (void)ws_size;
    const float* x          = (const float*)d_in[0];
    const float* norm_w     = (const float*)d_in[1];
    const float* in_proj_w  = (const float*)d_in[2];
    const float* conv_w     = (const float*)d_in[3];
    const float* conv_b     = (const float*)d_in[4];
    const float* dt_bias    = (const float*)d_in[5];
    const float* A_log      = (const float*)d_in[6];
    const float* Dh         = (const float*)d_in[7];
    const float* gnorm_w    = (const float*)d_in[8];
    const float* out_proj_w = (const float*)d_in[9];
    float* out = (float*)d_out;
    float* ws = (float*)d_ws;

    // workspace layout (float slots); total ~90 MB
    float* zxb_f   = ws;                       //  8,978,432 (bf16 4096x4384)
    float* xbc_f   = zxb_f   + 8978432;        //  4,718,592 (bf16 4096x2304)
    float* dtv     = xbc_f   + 4718592;        //    131,072
    float* acs     = dtv     + 131072;         //    131,072
    float* g2_f    = acs     + 131072;         //    524,288 (bf16 [bc][l][s])
    float* state_f = g2_f    + 524288;         //  2,097,152 (bf16 [bc][h][p][n])
    float* bt_f    = state_f + 2097152;        //    262,144 (bf16 [bc][n][l])
    float* regU    = bt_f    + 262144;         //  4,390,912 (xn_bf+wi_bf, later ybf)
    float* wo_f    = regU    + 4390912;        //  1,048,576 (wo_bf)
    float* ssq     = wo_f    + 1048576;        //      4,096

    ushort* zxb_bf = (ushort*)zxb_f;
    ushort* xBC_bf = (ushort*)xbc_f;
    ushort* G2b    = (ushort*)g2_f;
    ushort* state  = (ushort*)state_f;
    ushort* Bt     = (ushort*)bt_f;
    ushort* xn_bf  = (ushort*)regU;                 // 4096x1024 [dead after in_proj]
    ushort* wi_bf  = (ushort*)(regU + 2097152);     // 4480x1024 [dead after in_proj]
    ushort* ybf    = (ushort*)regU;                 // 4096x2048 [born at ssd_y]
    ushort* wo_bf  = (ushort*)wo_f;

    // 0. prologue (wi cvt, wo'·gw cvt, rmsnorm, ssq=0)
    prologue_kernel<<<dim3(10640), 256, 0, stream>>>(
        x, norm_w, in_proj_w, out_proj_w, gnorm_w, xn_bf, wi_bf, wo_bf, ssq);

    // 1. zxbcdt = xn @ in_proj_w^T -> bf16 (M=4096, N=4384 pad 4480, K=1024)
    //    128x128 tile: 32x35 = 1120 blocks (+XCD swizzle)
    gemm_bf16_kernel<<<dim3(32 * 35), 256, 0, stream>>>(
        xn_bf, DMODEL, 0, wi_bf, DMODEL, 0,
        zxb_bf, DINP, 0, 1, nullptr, nullptr, 32, 35, DINP, DMODEL);

    // 2. conv (main + tail blocks) + dt-softplus+cumsum
    conv_acs_kernel<<<dim3(NROWS + 512 + BB * NCH * NHEADS), 256, 0, stream>>>(
        zxb_bf, conv_w, conv_b, xBC_bf, dt_bias, A_log, dtv, acs);

    // 3. Bt (B^T operand, reads conv'd xBC)
    prep_b_kernel<<<dim3(BB * NCH, 2), 256, 0, stream>>>(xBC_bf, Bt);

    // 4. G2[bc][l][s] = C_l . B_s -> bf16 (batched; M=N=256, K=128; 128x64 tile)
    gemm_bf16_s_kernel<<<dim3(8, 1, BB * NCH), 256, 0, stream>>>(
        xBC_bf + DINNER + DSTATE, CONVD, (long)CHUNK * CONVD,
        xBC_bf + DINNER, CONVD, (long)CHUNK * CONVD,
        G2b, CHUNK, (long)CHUNK * CHUNK, 1, nullptr, nullptr, 2, 4, CHUNK, DSTATE);

    // 5. chunk states (MFMA, in-LDS transpose) -> bf16 state
    chunk_state_mfma_kernel<<<dim3(BB * NCH, NHEADS), 256, 0, stream>>>(
        xBC_bf, Bt, dtv, acs, state);

    // 6. inter-chunk scan (in place, bf16)
    state_scan_kernel<<<dim3(BB * NHEADS * 8192 / 256), 256, 0, stream>>>(state, acs);

    // 7. Y (MFMA diag+off, warp-balanced, row-split z=2 -> 1024 blocks)
    ssd_y_mfma_kernel<<<dim3(BB * NCH, NHEADS, 2), 256, 0, stream>>>(
        xBC_bf, G2b, acs, state, zxb_bf, dtv, Dh, ybf, ssq);

    // 8. out = x + rsqrt(ssq/D+eps)*(y @ (gw·Wo)^T)
    //    64x64 tile: 64x16 = 1024 blocks -> 4 resident/CU
    gemm64_kernel<<<dim3(64 * 16), 256, 0, stream>>>(
        ybf, DINNER, wo_bf, DINNER, out, DMODEL, x, ssq, 64, 16, 2048);
}

// Round 12
// 280.625 us; speedup vs baseline: 1.0454x; 1.0454x over previous
//
#include <hip/hip_runtime.h>
#include <hip/hip_bf16.h>

// ---- problem constants ----
#define BB      2
#define LSEQ    2048
#define DMODEL  1024
#define DSTATE  128
#define DCONV   4
#define HEADDIM 64
#define DINNER  2048      // EXP*DMODEL
#define NHEADS  32        // DINNER/HEADDIM
#define CONVD   2304      // DINNER + 2*DSTATE
#define DINP    4384      // 2*DINNER + 2*DSTATE + NHEADS
#define CHUNK   256
#define NCH     8         // LSEQ/CHUNK
#define NROWS   4096      // BB*LSEQ
#define EPSF    1e-5f
#define TPAD    264       // LDS transpose row pitch (ushort)

typedef __attribute__((ext_vector_type(8))) short bf16x8;
typedef __attribute__((ext_vector_type(4))) float f32x4;

#define ASYNC_COPY16(gptr, lptr) \
    __builtin_amdgcn_global_load_lds((const __attribute__((address_space(1))) void*)(gptr), \
                                     (__attribute__((address_space(3))) void*)(lptr), 16, 0, 0)

__device__ __forceinline__ ushort f2bf(float f) {
    __hip_bfloat16 h = __float2bfloat16(f);
    return *(ushort*)&h;
}
__device__ __forceinline__ float bf2f(ushort u) {
    return __uint_as_float(((unsigned)u) << 16);
}
// truncation (toward zero) float->bf16: 1 op, <=2^-8 rel err — hot paths only
__device__ __forceinline__ short tb(float f) { return (short)(__float_as_uint(f) >> 16); }

// XCD-aware bijective pid swizzle: consecutive tiles share one XCD's L2.
// [round-6 proven: gemm1 FETCH 77->35MB, dur 59->52.6us]
__device__ __forceinline__ int xcd_swizzle(int pid, int nwg) {
    return ((nwg & 7) == 0) ? (pid & 7) * (nwg >> 3) + (pid >> 3) : pid;
}

// ============================================================
// Prologue: wi cvt (padded to 4480 rows), wo cvt (pre-scaled by gnorm_w),
// rmsnorm->bf16, ssq zeroing.
// grid: [0,4480) wi | [4480,6528) wo | [6528,10624) rmsnorm | [10624,10640) ssq=0
// ============================================================
__global__ __launch_bounds__(256) void prologue_kernel(
    const float* __restrict__ x, const float* __restrict__ norm_w,
    const float* __restrict__ in_proj_w, const float* __restrict__ out_proj_w,
    const float* __restrict__ gnorm_w,
    ushort* __restrict__ xn_bf, ushort* __restrict__ wi_bf,
    ushort* __restrict__ wo_bf, float* __restrict__ ssq)
{
    int bid = blockIdx.x;
    if (bid < 4480) {                 // wi: 4480x1024 bf16, zero-pad rows >= 4384
        long i4 = ((long)bid * 256 + threadIdx.x) * 4;
        int n = (int)(i4 >> 10);
        long k = i4 & 1023;
        ushort4 o;
        if (n < DINP) {
            float4 v = *(const float4*)(in_proj_w + ((long)n << 10) + k);
            o.x = f2bf(v.x); o.y = f2bf(v.y); o.z = f2bf(v.z); o.w = f2bf(v.w);
        } else { o.x = o.y = o.z = o.w = 0; }
        *(ushort4*)(wi_bf + i4) = o;
    } else if (bid < 6528) {          // wo': 1024x2048 bf16, folded gnorm_w
        long i4 = ((long)(bid - 4480) * 256 + threadIdx.x) * 4;
        int k = (int)(i4 & 2047);
        float4 v = *(const float4*)(out_proj_w + i4);
        float4 g = *(const float4*)(gnorm_w + k);
        ushort4 o;
        o.x = f2bf(v.x * g.x); o.y = f2bf(v.y * g.y);
        o.z = f2bf(v.z * g.z); o.w = f2bf(v.w * g.w);
        *(ushort4*)(wo_bf + i4) = o;
    } else if (bid < 10624) {         // rmsnorm row -> bf16
        int row = bid - 6528;
        const float* xr = x + (long)row * DMODEL;
        float4 v = *(const float4*)(xr + threadIdx.x * 4);
        float ss = v.x*v.x + v.y*v.y + v.z*v.z + v.w*v.w;
        for (int off = 32; off; off >>= 1) ss += __shfl_down(ss, off, 64);
        __shared__ float red[4];
        if ((threadIdx.x & 63) == 0) red[threadIdx.x >> 6] = ss;
        __syncthreads();
        float tot = red[0] + red[1] + red[2] + red[3];
        float scale = rsqrtf(tot / (float)DMODEL + EPSF);
        float4 wv = *(const float4*)(norm_w + threadIdx.x * 4);
        ushort4 o;
        o.x = f2bf(v.x * scale * wv.x); o.y = f2bf(v.y * scale * wv.y);
        o.z = f2bf(v.z * scale * wv.z); o.w = f2bf(v.w * scale * wv.w);
        *(ushort4*)(xn_bf + (long)row * DMODEL + threadIdx.x * 4) = o;
    } else {                          // ssq = 0
        ssq[(bid - 10624) * 256 + threadIdx.x] = 0.f;
    }
}

// ============================================================
// Big bf16 MFMA NT GEMM: 128x128 tile, BK=64, 32 MFMA/K-step.
// [proven: 52.6us gemm1, 0 conflicts, FETCH 35MB w/ swizzle]
// ============================================================
__global__ __launch_bounds__(256, 3) void gemm_bf16_kernel(
    const ushort* __restrict__ A, int lda, long sA,
    const ushort* __restrict__ W, int ldw, long sW,
    void* __restrict__ Cout, int ldc, long sC, int c_bf16,
    const float* __restrict__ resid, const float* __restrict__ rowscale,
    int mtiles, int ntiles, int N, int K)
{
    __shared__ __align__(16) char smem[34816];
    ushort* As = (ushort*)smem;          // 128*64 ushort = 16 KB
    ushort* Bs = As + 128 * 64;          // 128*64 ushort = 16 KB
    ushort* tu = (ushort*)smem;          // epilogue bf16 tile [128][136] = 34 KB
    float*  tf = (float*)smem;           // epilogue fp32 tile [64][132] = 33 KB

    const int t = threadIdx.x;
    const int lane = t & 63;
    const int w = t >> 6;
    const int wm = w & 1, wn = w >> 1;
    const int lm = lane & 15, quad = lane >> 4;

    int pid = xcd_swizzle(blockIdx.x, gridDim.x);
    const int GM = 8;
    int width = GM * ntiles;
    int group = pid / width;
    int first_m = group * GM;
    int gsz = mtiles - first_m; if (gsz > GM) gsz = GM;
    int mt = first_m + (pid % width) % gsz;
    int nt = (pid % width) / gsz;
    const int m0 = mt * 128, n0 = nt * 128;

    A += (long)blockIdx.z * sA;
    W += (long)blockIdx.z * sW;

    const ushort* ga[4]; const ushort* gw[4];
#pragma unroll
    for (int i = 0; i < 4; ++i) {
        int s = i * 256 + t;
        int row = s >> 3;
        int kseg = (s & 7) ^ (row & 7);
        ga[i] = A + (long)(m0 + row) * lda + kseg * 8;
        gw[i] = W + (long)(n0 + row) * ldw + kseg * 8;
    }

    f32x4 acc[4][4];
    f32x4 zero4 = {0.f, 0.f, 0.f, 0.f};
#pragma unroll
    for (int i = 0; i < 4; ++i)
#pragma unroll
        for (int j = 0; j < 4; ++j) acc[i][j] = zero4;

    int arow8[4], arow7[4], brow8[4], brow7[4];
#pragma unroll
    for (int i = 0; i < 4; ++i) {
        int ar = wm * 64 + i * 16 + lm;
        arow8[i] = ar * 8; arow7[i] = ar & 7;
        int br = wn * 64 + i * 16 + lm;
        brow8[i] = br * 8; brow7[i] = br & 7;
    }

    for (int k0 = 0; k0 < K; k0 += 64) {
#pragma unroll
        for (int i = 0; i < 4; ++i) {
            ASYNC_COPY16(ga[i], &As[(i * 256 + w * 64) * 8]);
            ga[i] += 64;
        }
#pragma unroll
        for (int i = 0; i < 4; ++i) {
            ASYNC_COPY16(gw[i], &Bs[(i * 256 + w * 64) * 8]);
            gw[i] += 64;
        }
        __syncthreads();
#pragma unroll
        for (int ks = 0; ks < 2; ++ks) {
            bf16x8 af[4], bfr[4];
#pragma unroll
            for (int i = 0; i < 4; ++i)
                af[i]  = *(const bf16x8*)&As[(arow8[i] + ((ks * 4 + quad) ^ arow7[i])) * 8];
#pragma unroll
            for (int i = 0; i < 4; ++i)
                bfr[i] = *(const bf16x8*)&Bs[(brow8[i] + ((ks * 4 + quad) ^ brow7[i])) * 8];
#pragma unroll
            for (int im = 0; im < 4; ++im)
#pragma unroll
                for (int in = 0; in < 4; ++in)
                    acc[im][in] = __builtin_amdgcn_mfma_f32_16x16x32_bf16(
                        af[im], bfr[in], acc[im][in], 0, 0, 0);
        }
        __syncthreads();
    }

    // ---- epilogue: LDS bounce -> coalesced full-line stores ----
    if (c_bf16) {
        ushort* C = (ushort*)Cout + (long)blockIdx.z * sC;
#pragma unroll
        for (int mi = 0; mi < 4; ++mi)
#pragma unroll
            for (int ni = 0; ni < 4; ++ni) {
                int c = wn * 64 + ni * 16 + lm;
#pragma unroll
                for (int i = 0; i < 4; ++i) {
                    int r = wm * 64 + mi * 16 + quad * 4 + i;
                    tu[r * 136 + c] = f2bf(acc[mi][ni][i]);
                }
            }
        __syncthreads();
        int r = t >> 1, cb = (t & 1) * 64;
        long rowbase = (long)(m0 + r) * ldc + n0 + cb;
#pragma unroll
        for (int q = 0; q < 8; ++q) {
            int gcol = n0 + cb + q * 8;
            if (gcol < N)
                *(bf16x8*)(C + rowbase + q * 8) =
                    *(const bf16x8*)&tu[r * 136 + cb + q * 8];
        }
    } else {
        float* C = (float*)Cout + (long)blockIdx.z * sC;
#pragma unroll
        for (int p = 0; p < 2; ++p) {
            if (wm == p) {
#pragma unroll
                for (int mi = 0; mi < 4; ++mi)
#pragma unroll
                    for (int i = 0; i < 4; ++i) {
                        int r = mi * 16 + quad * 4 + i;
                        float s = 1.f;
                        if (rowscale)
                            s = rsqrtf(rowscale[m0 + p * 64 + r] * (1.f / (float)DINNER) + EPSF);
#pragma unroll
                        for (int ni = 0; ni < 4; ++ni) {
                            int c = wn * 64 + ni * 16 + lm;
                            tf[r * 132 + c] = acc[mi][ni][i] * s;
                        }
                    }
            }
            __syncthreads();
            int r2 = t >> 2, cb = (t & 3) * 32;
            long gbase = (long)(m0 + p * 64 + r2) * ldc + n0 + cb;
#pragma unroll
            for (int q = 0; q < 8; ++q) {
                float4 v = *(const float4*)&tf[r2 * 132 + cb + q * 4];
                if (resid) {
                    float4 rv = *(const float4*)(resid + gbase + q * 4);
                    v.x += rv.x; v.y += rv.y; v.z += rv.z; v.w += rv.w;
                }
                *(float4*)(C + gbase + q * 4) = v;
            }
            __syncthreads();
        }
    }
}

// ============================================================
// Small bf16 MFMA NT GEMM: 128x64 tile, 16 MFMA/K-step — used for
// gemm4 (bf16-out batched tiny GEMM).
// ============================================================
__global__ __launch_bounds__(256, 4) void gemm_bf16_s_kernel(
    const ushort* __restrict__ A, int lda, long sA,
    const ushort* __restrict__ W, int ldw, long sW,
    void* __restrict__ Cout, int ldc, long sC, int c_bf16,
    const float* __restrict__ resid, const float* __restrict__ rowscale,
    int mtiles, int ntiles, int N, int K)
{
    __shared__ __align__(16) char smem[24576];
    ushort* As = (ushort*)smem;          // 128*64 ushort = 16 KB
    ushort* Bs = As + 128 * 64;          //  64*64 ushort =  8 KB
    ushort* tu = (ushort*)smem;          // epilogue bf16 tile [128][72]
    float*  tf = (float*)smem;           // epilogue fp32 tile [64][68]

    const int t = threadIdx.x;
    const int lane = t & 63;
    const int w = t >> 6;
    const int wm = w & 1, wn = w >> 1;
    const int lm = lane & 15, quad = lane >> 4;

    int pid = xcd_swizzle(blockIdx.x, gridDim.x);
    const int GM = 8;
    int width = GM * ntiles;
    int group = pid / width;
    int first_m = group * GM;
    int gsz = mtiles - first_m; if (gsz > GM) gsz = GM;
    int mt = first_m + (pid % width) % gsz;
    int nt = (pid % width) / gsz;
    const int m0 = mt * 128, n0 = nt * 64;

    A += (long)blockIdx.z * sA;
    W += (long)blockIdx.z * sW;

    const ushort* ga[4]; const ushort* gw[2];
#pragma unroll
    for (int i = 0; i < 4; ++i) {
        int s = i * 256 + t;
        int row = s >> 3;
        int kseg = (s & 7) ^ (row & 7);
        ga[i] = A + (long)(m0 + row) * lda + kseg * 8;
    }
#pragma unroll
    for (int i = 0; i < 2; ++i) {
        int s = i * 256 + t;
        int row = s >> 3;
        int kseg = (s & 7) ^ (row & 7);
        gw[i] = W + (long)(n0 + row) * ldw + kseg * 8;
    }

    f32x4 acc[4][2];
    f32x4 zero4 = {0.f, 0.f, 0.f, 0.f};
#pragma unroll
    for (int i = 0; i < 4; ++i) { acc[i][0] = zero4; acc[i][1] = zero4; }

    int arow8[4], arow7[4], brow8[2], brow7[2];
#pragma unroll
    for (int i = 0; i < 4; ++i) {
        int ar = wm * 64 + i * 16 + lm;
        arow8[i] = ar * 8; arow7[i] = ar & 7;
    }
#pragma unroll
    for (int i = 0; i < 2; ++i) {
        int br = wn * 32 + i * 16 + lm;
        brow8[i] = br * 8; brow7[i] = br & 7;
    }

    for (int k0 = 0; k0 < K; k0 += 64) {
#pragma unroll
        for (int i = 0; i < 4; ++i) {
            ASYNC_COPY16(ga[i], &As[(i * 256 + w * 64) * 8]);
            ga[i] += 64;
        }
#pragma unroll
        for (int i = 0; i < 2; ++i) {
            ASYNC_COPY16(gw[i], &Bs[(i * 256 + w * 64) * 8]);
            gw[i] += 64;
        }
        __syncthreads();
#pragma unroll
        for (int ks = 0; ks < 2; ++ks) {
            bf16x8 af[4], bfr[2];
#pragma unroll
            for (int i = 0; i < 4; ++i)
                af[i]  = *(const bf16x8*)&As[(arow8[i] + ((ks * 4 + quad) ^ arow7[i])) * 8];
#pragma unroll
            for (int i = 0; i < 2; ++i)
                bfr[i] = *(const bf16x8*)&Bs[(brow8[i] + ((ks * 4 + quad) ^ brow7[i])) * 8];
#pragma unroll
            for (int im = 0; im < 4; ++im)
#pragma unroll
                for (int in = 0; in < 2; ++in)
                    acc[im][in] = __builtin_amdgcn_mfma_f32_16x16x32_bf16(
                        af[im], bfr[in], acc[im][in], 0, 0, 0);
        }
        __syncthreads();
    }

    // ---- epilogue: LDS bounce -> coalesced full-line stores ----
    if (c_bf16) {
        ushort* C = (ushort*)Cout + (long)blockIdx.z * sC;
#pragma unroll
        for (int mi = 0; mi < 4; ++mi)
#pragma unroll
            for (int ni = 0; ni < 2; ++ni) {
                int c = wn * 32 + ni * 16 + lm;
#pragma unroll
                for (int i = 0; i < 4; ++i) {
                    int r = wm * 64 + mi * 16 + quad * 4 + i;
                    tu[r * 72 + c] = f2bf(acc[mi][ni][i]);
                }
            }
        __syncthreads();
        int r = t >> 1, cb = (t & 1) * 32;
        long rowbase = (long)(m0 + r) * ldc + n0 + cb;
#pragma unroll
        for (int q = 0; q < 4; ++q) {
            int gcol = n0 + cb + q * 8;
            if (gcol < N)
                *(bf16x8*)(C + rowbase + q * 8) =
                    *(const bf16x8*)&tu[r * 72 + cb + q * 8];
        }
    } else {
        float* C = (float*)Cout + (long)blockIdx.z * sC;
#pragma unroll
        for (int p = 0; p < 2; ++p) {
            if (wm == p) {
#pragma unroll
                for (int mi = 0; mi < 4; ++mi)
#pragma unroll
                    for (int i = 0; i < 4; ++i) {
                        int r = mi * 16 + quad * 4 + i;
                        float s = 1.f;
                        if (rowscale)
                            s = rsqrtf(rowscale[m0 + p * 64 + r] * (1.f / (float)DINNER) + EPSF);
#pragma unroll
                        for (int ni = 0; ni < 2; ++ni) {
                            int c = wn * 32 + ni * 16 + lm;
                            tf[r * 68 + c] = acc[mi][ni][i] * s;
                        }
                    }
            }
            __syncthreads();
            int r2 = t >> 2, cb = (t & 3) * 16;
            long gbase = (long)(m0 + p * 64 + r2) * ldc + n0 + cb;
#pragma unroll
            for (int q = 0; q < 4; ++q) {
                float4 v = *(const float4*)&tf[r2 * 68 + cb + q * 4];
                if (resid) {
                    float4 rv = *(const float4*)(resid + gbase + q * 4);
                    v.x += rv.x; v.y += rv.y; v.z += rv.z; v.w += rv.w;
                }
                *(float4*)(C + gbase + q * 4) = v;
            }
            __syncthreads();
        }
    }
}

// ============================================================
// 64x64-tile bf16 MFMA NT GEMM for gemm8 (latency-bound K=2048):
// 1024 blocks -> 4 resident/CU. [round-10 proven: gemm8 out of top-5]
// ============================================================
__global__ __launch_bounds__(256, 4) void gemm64_kernel(
    const ushort* __restrict__ A, int lda,
    const ushort* __restrict__ W, int ldw,
    float* __restrict__ Cout, int ldc,
    const float* __restrict__ resid, const float* __restrict__ rowscale,
    int mtiles, int ntiles, int K)
{
    __shared__ __align__(16) char smem[17408];
    ushort* As = (ushort*)smem;          // 64*64 ushort = 8 KB
    ushort* Bs = As + 64 * 64;           // 8 KB
    float*  tf = (float*)smem;           // epilogue fp32 tile [64][68] = 17408 B

    const int t = threadIdx.x;
    const int lane = t & 63;
    const int w = t >> 6;
    const int wm = w & 1, wn = w >> 1;
    const int lm = lane & 15, quad = lane >> 4;

    int pid = xcd_swizzle(blockIdx.x, gridDim.x);
    const int GM = 8;
    int width = GM * ntiles;
    int group = pid / width;
    int first_m = group * GM;
    int gsz = mtiles - first_m; if (gsz > GM) gsz = GM;
    int mt = first_m + (pid % width) % gsz;
    int nt = (pid % width) / gsz;
    const int m0 = mt * 64, n0 = nt * 64;

    const ushort* ga[2]; const ushort* gw[2];
#pragma unroll
    for (int i = 0; i < 2; ++i) {
        int s = i * 256 + t;
        int row = s >> 3;
        int kseg = (s & 7) ^ (row & 7);
        ga[i] = A + (long)(m0 + row) * lda + kseg * 8;
        gw[i] = W + (long)(n0 + row) * ldw + kseg * 8;
    }

    f32x4 acc[2][2];
    f32x4 zero4 = {0.f, 0.f, 0.f, 0.f};
    acc[0][0] = zero4; acc[0][1] = zero4;
    acc[1][0] = zero4; acc[1][1] = zero4;

    int arow8[2], arow7[2], brow8[2], brow7[2];
#pragma unroll
    for (int i = 0; i < 2; ++i) {
        int ar = wm * 32 + i * 16 + lm;
        arow8[i] = ar * 8; arow7[i] = ar & 7;
        int br = wn * 32 + i * 16 + lm;
        brow8[i] = br * 8; brow7[i] = br & 7;
    }

    for (int k0 = 0; k0 < K; k0 += 64) {
#pragma unroll
        for (int i = 0; i < 2; ++i) {
            ASYNC_COPY16(ga[i], &As[(i * 256 + w * 64) * 8]);
            ga[i] += 64;
            ASYNC_COPY16(gw[i], &Bs[(i * 256 + w * 64) * 8]);
            gw[i] += 64;
        }
        __syncthreads();
#pragma unroll
        for (int ks = 0; ks < 2; ++ks) {
            bf16x8 af[2], bfr[2];
#pragma unroll
            for (int i = 0; i < 2; ++i) {
                af[i]  = *(const bf16x8*)&As[(arow8[i] + ((ks * 4 + quad) ^ arow7[i])) * 8];
                bfr[i] = *(const bf16x8*)&Bs[(brow8[i] + ((ks * 4 + quad) ^ brow7[i])) * 8];
            }
#pragma unroll
            for (int im = 0; im < 2; ++im)
#pragma unroll
                for (int in = 0; in < 2; ++in)
                    acc[im][in] = __builtin_amdgcn_mfma_f32_16x16x32_bf16(
                        af[im], bfr[in], acc[im][in], 0, 0, 0);
        }
        __syncthreads();
    }

    // ---- epilogue: rowscale + resid, LDS bounce -> coalesced fp32 stores ----
#pragma unroll
    for (int mi = 0; mi < 2; ++mi)
#pragma unroll
        for (int i = 0; i < 4; ++i) {
            int r = wm * 32 + mi * 16 + quad * 4 + i;
            float s = rsqrtf(rowscale[m0 + r] * (1.f / (float)DINNER) + EPSF);
#pragma unroll
            for (int ni = 0; ni < 2; ++ni) {
                int c = wn * 32 + ni * 16 + lm;
                tf[r * 68 + c] = acc[mi][ni][i] * s;
            }
        }
    __syncthreads();
    int r2 = t >> 2, cb = (t & 3) * 16;
    long gbase = (long)(m0 + r2) * ldc + n0 + cb;
#pragma unroll
    for (int q = 0; q < 4; ++q) {
        float4 v = *(const float4*)&tf[r2 * 68 + cb + q * 4];
        float4 rv = *(const float4*)(resid + gbase + q * 4);
        v.x += rv.x; v.y += rv.y; v.z += rv.z; v.w += rv.w;
        *(float4*)(Cout + gbase + q * 4) = v;
    }
}

// ============================================================
// Merged conv+SiLU + dt-softplus/cumsum.
// Main conv: per-row layout (ch 0..2047, 8 ch/thread); 256-ch tail
// in 512 dedicated blocks (8 rows x 32 lanes).
// grid: [0,4096) conv main | [4096,4608) conv tail | [4608,5120) acs
// ============================================================
__device__ __forceinline__ void conv8_row(
    const ushort* __restrict__ zx, const float* __restrict__ cw,
    const float* __restrict__ cb, ushort* __restrict__ xBC_bf,
    int row, int l, int c)
{
    float4 cwv[8];
#pragma unroll
    for (int j = 0; j < 8; ++j) cwv[j] = *(const float4*)(cw + (c + j) * 4);
    float acc[8];
    {
        float4 b0 = *(const float4*)(cb + c);
        float4 b1 = *(const float4*)(cb + c + 4);
        acc[0] = b0.x; acc[1] = b0.y; acc[2] = b0.z; acc[3] = b0.w;
        acc[4] = b1.x; acc[5] = b1.y; acc[6] = b1.z; acc[7] = b1.w;
    }
#pragma unroll
    for (int k = 0; k < DCONV; ++k) {
        int ls = l + k - (DCONV - 1);
        if (ls >= 0) {
            const ushort* zr = zx + (long)(row + k - (DCONV - 1)) * DINP + DINNER + c;
            ushort4 a = *(const ushort4*)zr;
            ushort4 b = *(const ushort4*)(zr + 4);
            acc[0] += bf2f(a.x) * ((const float*)&cwv[0])[k];
            acc[1] += bf2f(a.y) * ((const float*)&cwv[1])[k];
            acc[2] += bf2f(a.z) * ((const float*)&cwv[2])[k];
            acc[3] += bf2f(a.w) * ((const float*)&cwv[3])[k];
            acc[4] += bf2f(b.x) * ((const float*)&cwv[4])[k];
            acc[5] += bf2f(b.y) * ((const float*)&cwv[5])[k];
            acc[6] += bf2f(b.z) * ((const float*)&cwv[6])[k];
            acc[7] += bf2f(b.w) * ((const float*)&cwv[7])[k];
        }
    }
    ushort o[8];
#pragma unroll
    for (int j = 0; j < 8; ++j)
        o[j] = f2bf(acc[j] / (1.f + __expf(-acc[j])));
    ushort* dst = xBC_bf + (long)row * CONVD + c;
    *(ushort4*)dst = *(ushort4*)&o[0];
    *(ushort4*)(dst + 4) = *(ushort4*)&o[4];
}

__global__ __launch_bounds__(256) void conv_acs_kernel(
    const ushort* __restrict__ zx, const float* __restrict__ cw,
    const float* __restrict__ cb, ushort* __restrict__ xBC_bf,
    const float* __restrict__ dt_bias, const float* __restrict__ A_log,
    float* __restrict__ dtv, float* __restrict__ Acs)
{
    int bid = blockIdx.x;
    int t = threadIdx.x;
    if (bid < NROWS) {
        // ---- conv main: ch 0..2047, one row per block ----
        int row = bid;
        int l = row & (LSEQ - 1);
        conv8_row(zx, cw, cb, xBC_bf, row, l, t * 8);
    } else if (bid < NROWS + 512) {
        // ---- conv tail: ch 2048..2303, 8 rows per block ----
        int row = (bid - NROWS) * 8 + (t >> 5);
        int c = 2048 + (t & 31) * 8;
        int l = row & (LSEQ - 1);
        conv8_row(zx, cw, cb, xBC_bf, row, l, c);
    } else {
        // ---- dt softplus + per-chunk cumsum ----
        __shared__ float buf[2 * CHUNK];
        int idx = bid - (NROWS + 512);
        int bc = idx >> 5, h = idx & 31;
        int l = t;
        int row = bc * CHUNK + l;
        float v = bf2f(zx[(long)row * DINP + (DINP - NHEADS) + h]) + dt_bias[h];
        float d = (v > 20.f) ? v : log1pf(__expf(v));
        dtv[row * NHEADS + h] = d;
        float a = -d * __expf(A_log[h]);
        buf[l] = a; __syncthreads();
        int src = 0;
        for (int off = 1; off < CHUNK; off <<= 1) {
            float vv = buf[src * CHUNK + l];
            if (l >= off) vv += buf[src * CHUNK + l - off];
            buf[(src ^ 1) * CHUNK + l] = vv;
            __syncthreads();
            src ^= 1;
        }
        Acs[(bc * NHEADS + h) * CHUNK + l] = buf[src * CHUNK + l];
    }
}

// ============================================================
// Bt[bc][n][l] = B[l][n] (K-contiguous operand, shared by all heads)
// ============================================================
__global__ __launch_bounds__(256) void prep_b_kernel(
    const ushort* __restrict__ xBC_bf, ushort* __restrict__ Bt)
{
    int bc = blockIdx.x, half = blockIdx.y;
    int t = threadIdx.x;
    int row0 = bc * CHUNK;
    __shared__ ushort tB[64 * TPAD];
    int src_c0 = DINNER + half * 64;
    for (int iter = 0; iter < 8; ++iter) {
        int l = iter * 32 + (t >> 3);
        int cc = (t & 7) * 8;
        ushort u[8];
        *(ushort4*)&u[0] = *(const ushort4*)(xBC_bf + (long)(row0 + l) * CONVD + src_c0 + cc);
        *(ushort4*)&u[4] = *(const ushort4*)(xBC_bf + (long)(row0 + l) * CONVD + src_c0 + cc + 4);
#pragma unroll
        for (int j = 0; j < 8; ++j) tB[(cc + j) * TPAD + l] = u[j];
    }
    __syncthreads();
    int r = t >> 2, seg = (t & 3) * 64;
    ushort* dst = Bt + ((long)bc * DSTATE + half * 64 + r) * CHUNK + seg;
    const ushort* s1 = &tB[r * TPAD + seg];
#pragma unroll
    for (int q = 0; q < 16; ++q)
        *(ushort4*)(dst + q * 4) = *(const ushort4*)(s1 + q * 4);
}

// ============================================================
// Chunk state via MFMA with in-LDS X transpose:
//   S_t[p][n] = sum_l exp(T-acs_l)*dt_l*X[l,p] * Bt[n][l]  -> bf16
// ============================================================
__global__ __launch_bounds__(256) void chunk_state_mfma_kernel(
    const ushort* __restrict__ xBC_bf, const ushort* __restrict__ Bt,
    const float* __restrict__ dtv, const float* __restrict__ acs,
    ushort* __restrict__ state)
{
    int bc = blockIdx.x, h = blockIdx.y;
    int t = threadIdx.x, lane = t & 63, w = t >> 6;
    int lm = lane & 15, quad = lane >> 4;
    int row0 = bc * CHUNK;
    __shared__ ushort xt[64 * TPAD];
    __shared__ float cl[CHUNK];
    {
        float a = acs[(bc * NHEADS + h) * CHUNK + t];
        float T = acs[(bc * NHEADS + h) * CHUNK + CHUNK - 1];
        cl[t] = __expf(T - a) * dtv[(row0 + t) * NHEADS + h];
    }
    __syncthreads();
    for (int iter = 0; iter < 8; ++iter) {
        int l = iter * 32 + (t >> 3);
        int cc = (t & 7) * 8;
        ushort u[8];
        *(ushort4*)&u[0] = *(const ushort4*)(xBC_bf + (long)(row0 + l) * CONVD + h * HEADDIM + cc);
        *(ushort4*)&u[4] = *(const ushort4*)(xBC_bf + (long)(row0 + l) * CONVD + h * HEADDIM + cc + 4);
        float sc = cl[l];
#pragma unroll
        for (int j = 0; j < 8; ++j)
            xt[(cc + j) * TPAD + l] = (ushort)tb(bf2f(u[j]) * sc);
    }
    __syncthreads();

    const ushort* Bb = Bt + (long)bc * DSTATE * CHUNK;
    f32x4 acc[4][2];
    f32x4 zero4 = {0.f, 0.f, 0.f, 0.f};
#pragma unroll
    for (int i = 0; i < 4; ++i) { acc[i][0] = zero4; acc[i][1] = zero4; }

    for (int kt = 0; kt < 8; ++kt) {
        int k = kt * 32 + quad * 8;
        bf16x8 af[4], bfr[2];
#pragma unroll
        for (int mi = 0; mi < 4; ++mi)
            af[mi] = *(const bf16x8*)&xt[(mi * 16 + lm) * TPAD + k];
#pragma unroll
        for (int nj = 0; nj < 2; ++nj)
            bfr[nj] = *(const bf16x8*)(Bb + (long)(w * 32 + nj * 16 + lm) * CHUNK + k);
#pragma unroll
        for (int mi = 0; mi < 4; ++mi)
#pragma unroll
            for (int nj = 0; nj < 2; ++nj)
                acc[mi][nj] = __builtin_amdgcn_mfma_f32_16x16x32_bf16(
                    af[mi], bfr[nj], acc[mi][nj], 0, 0, 0);
    }
    ushort* sp = state + (long)(bc * NHEADS + h) * (DSTATE * HEADDIM);
#pragma unroll
    for (int mi = 0; mi < 4; ++mi)
#pragma unroll
        for (int nj = 0; nj < 2; ++nj) {
            int n = w * 32 + nj * 16 + lm;
#pragma unroll
            for (int i = 0; i < 4; ++i) {
                int p = mi * 16 + quad * 4 + i;
                sp[p * DSTATE + n] = f2bf(acc[mi][nj][i]);
            }
        }
}

// ============================================================
// Inter-chunk scan (in place on bf16 states, fp32 accumulator)
// ============================================================
__global__ __launch_bounds__(256) void state_scan_kernel(
    ushort* __restrict__ state, const float* __restrict__ Acs)
{
    long flat = (long)blockIdx.x * 256 + threadIdx.x;
    int e = (int)(flat & 8191);
    int bh = (int)(flat >> 13);
    int b = bh >> 5, h = bh & 31;
    float S = 0.f;
    for (int c = 0; c < NCH; ++c) {
        int bc = b * NCH + c;
        long idx = ((long)(bc * NHEADS + h)) * 8192 + e;
        float T = Acs[(bc * NHEADS + h) * CHUNK + CHUNK - 1];
        float tmp = bf2f(state[idx]);
        state[idx] = f2bf(S);
        S = S * __expf(T) + tmp;
    }
}

// ============================================================
// SSD Y via MFMA (in-LDS Xdt transpose): Y = P@Xdt + (C*eAl)@S^T,
// then +D*xh, silu(z) gate, bf16 store + per-row ssq atomics.
// Warp-balanced causal mapping: warp w owns rows {mi*64 + w*16 + r}
// -> phase-A critical path 20 MFMA-groups (16/16/20/20 per warp).
// [round-9/10 proven config; z-split reverted after round-11 regression]
// ============================================================
__global__ __launch_bounds__(256) void ssd_y_mfma_kernel(
    const ushort* __restrict__ xBC_bf, const ushort* __restrict__ G2b,
    const float* __restrict__ acs, const ushort* __restrict__ state,
    const ushort* __restrict__ zxb, const float* __restrict__ dtv,
    const float* __restrict__ Dh, ushort* __restrict__ ybf,
    float* __restrict__ ssq)
{
    int bc = blockIdx.x, h = blockIdx.y;
    int t = threadIdx.x, lane = t & 63, w = t >> 6;
    int lm = lane & 15, quad = lane >> 4;
    int row0 = bc * CHUNK;
    __shared__ ushort xt[64 * TPAD];
    __shared__ float acs_s[CHUNK];
    __shared__ float dl[CHUNK];
    acs_s[t] = acs[(bc * NHEADS + h) * CHUNK + t];
    dl[t] = dtv[(row0 + t) * NHEADS + h];
    __syncthreads();
    // transpose X chunk (dt-scaled) into LDS [p][l]
    for (int iter = 0; iter < 8; ++iter) {
        int l = iter * 32 + (t >> 3);
        int cc = (t & 7) * 8;
        ushort u[8];
        *(ushort4*)&u[0] = *(const ushort4*)(xBC_bf + (long)(row0 + l) * CONVD + h * HEADDIM + cc);
        *(ushort4*)&u[4] = *(const ushort4*)(xBC_bf + (long)(row0 + l) * CONVD + h * HEADDIM + cc + 4);
        float sd = dl[l];
#pragma unroll
        for (int j = 0; j < 8; ++j)
            xt[(cc + j) * TPAD + l] = (ushort)tb(bf2f(u[j]) * sd);
    }
    __syncthreads();

    // balanced row base per mi: rows mi*64 + w*16 .. +15
    int rb[4];
    float acs_l[4], eAl[4];
#pragma unroll
    for (int mi = 0; mi < 4; ++mi) {
        rb[mi] = mi * 64 + w * 16;
        acs_l[mi] = acs_s[rb[mi] + lm];
        eAl[mi] = __expf(acs_l[mi]);
    }
    f32x4 acc[4][4];
    f32x4 zero4 = {0.f, 0.f, 0.f, 0.f};
#pragma unroll
    for (int i = 0; i < 4; ++i)
#pragma unroll
        for (int j = 0; j < 4; ++j) acc[i][j] = zero4;

    const ushort* g2 = G2b + (long)bc * (CHUNK * CHUNK);

    // ---- phase A: diagonal (causal), factored exps ----
    int ksmax = (192 + w * 16 + 15) >> 5;   // max over mi of (rb[mi]+15)/32
    for (int ks = 0; ks <= ksmax; ++ks) {
        int sq = ks * 32 + quad * 8;
        bf16x8 bfr[4];
#pragma unroll
        for (int ni = 0; ni < 4; ++ni)
            bfr[ni] = *(const bf16x8*)&xt[(ni * 16 + lm) * TPAD + sq];
        float base = acs_s[sq];
        float e8[8];
        e8[0] = 1.f;
#pragma unroll
        for (int j = 1; j < 8; ++j)
            e8[j] = __expf(fminf(base - acs_s[sq + j], 80.f));
#pragma unroll
        for (int mi = 0; mi < 4; ++mi) {
            int lmin = rb[mi];
            if (ks * 32 > lmin + 15) continue;
            int lv = lmin + lm;
            float em = __expf(fminf(acs_l[mi] - base, 0.f));
            bf16x8 g8 = *(const bf16x8*)(g2 + (long)lv * CHUNK + sq);
            bf16x8 af;
#pragma unroll
            for (int j = 0; j < 8; ++j) {
                float v = bf2f((ushort)g8[j]) * (em * e8[j]);
                af[j] = (sq + j > lv) ? (short)0 : tb(v);
            }
#pragma unroll
            for (int ni = 0; ni < 4; ++ni)
                acc[mi][ni] = __builtin_amdgcn_mfma_f32_16x16x32_bf16(
                    af, bfr[ni], acc[mi][ni], 0, 0, 0);
        }
    }

    // ---- phase B: off-diagonal (C*eAl @ S^T), bf16 state loads ----
    const ushort* sp = state + (long)(bc * NHEADS + h) * (DSTATE * HEADDIM);
    const ushort* Cb = xBC_bf + (long)row0 * CONVD + DINNER + DSTATE;
    for (int kt = 0; kt < 4; ++kt) {
        int n0 = kt * 32 + quad * 8;
        bf16x8 bfr[4];
#pragma unroll
        for (int ni = 0; ni < 4; ++ni)
            bfr[ni] = *(const bf16x8*)(sp + (long)(ni * 16 + lm) * DSTATE + n0);
#pragma unroll
        for (int mi = 0; mi < 4; ++mi) {
            int lv = rb[mi] + lm;
            bf16x8 cu = *(const bf16x8*)(Cb + (long)lv * CONVD + n0);
            bf16x8 ce;
            float e = eAl[mi];
#pragma unroll
            for (int j = 0; j < 8; ++j) ce[j] = tb(bf2f((ushort)cu[j]) * e);
#pragma unroll
            for (int ni = 0; ni < 4; ++ni)
                acc[mi][ni] = __builtin_amdgcn_mfma_f32_16x16x32_bf16(
                    ce, bfr[ni], acc[mi][ni], 0, 0, 0);
        }
    }

    // ---- epilogue: +D*xh, silu(z) gate, bf16 store + ssq ----
    float Dv = Dh[h];
#pragma unroll
    for (int mi = 0; mi < 4; ++mi)
#pragma unroll
        for (int i = 0; i < 4; ++i) {
            int l = rb[mi] + quad * 4 + i;
            long row = row0 + l;
            float ps = 0.f;
#pragma unroll
            for (int ni = 0; ni < 4; ++ni) {
                int p = ni * 16 + lm;
                float xh = bf2f(xBC_bf[row * CONVD + h * HEADDIM + p]);
                float z = bf2f(zxb[row * DINP + h * HEADDIM + p]);
                float o = (acc[mi][ni][i] + Dv * xh) * (z / (1.f + __expf(-z)));
                ps += o * o;
                ybf[row * DINNER + h * HEADDIM + p] = f2bf(o);
            }
#pragma unroll
            for (int m = 1; m < 16; m <<= 1) ps += __shfl_xor(ps, m, 64);
            if (lm == 0) atomicAdd(&ssq[row], ps);
        }
}

// ============================================================
// launch
// ============================================================
extern "C" void kernel_launch(void* const* d_in, const int* in_sizes, int n_in,
                              void* d_out, int out_size, void* d_ws, size_t ws_size,
                              hipStream_t stream)
{
    (void)in_sizes; (void)n_in; (void)out_size; (void)ws_size;
    const float* x          = (const float*)d_in[0];
    const float* norm_w     = (const float*)d_in[1];
    const float* in_proj_w  = (const float*)d_in[2];
    const float* conv_w     = (const float*)d_in[3];
    const float* conv_b     = (const float*)d_in[4];
    const float* dt_bias    = (const float*)d_in[5];
    const float* A_log      = (const float*)d_in[6];
    const float* Dh         = (const float*)d_in[7];
    const float* gnorm_w    = (const float*)d_in[8];
    const float* out_proj_w = (const float*)d_in[9];
    float* out = (float*)d_out;
    float* ws = (float*)d_ws;

    // workspace layout (float slots); total ~90 MB
    float* zxb_f   = ws;                       //  8,978,432 (bf16 4096x4384)
    float* xbc_f   = zxb_f   + 8978432;        //  4,718,592 (bf16 4096x2304)
    float* dtv     = xbc_f   + 4718592;        //    131,072
    float* acs     = dtv     + 131072;         //    131,072
    float* g2_f    = acs     + 131072;         //    524,288 (bf16 [bc][l][s])
    float* state_f = g2_f    + 524288;         //  2,097,152 (bf16 [bc][h][p][n])
    float* bt_f    = state_f + 2097152;        //    262,144 (bf16 [bc][n][l])
    float* regU    = bt_f    + 262144;         //  4,390,912 (xn_bf+wi_bf, later ybf)
    float* wo_f    = regU    + 4390912;        //  1,048,576 (wo_bf)
    float* ssq     = wo_f    + 1048576;        //      4,096

    ushort* zxb_bf = (ushort*)zxb_f;
    ushort* xBC_bf = (ushort*)xbc_f;
    ushort* G2b    = (ushort*)g2_f;
    ushort* state  = (ushort*)state_f;
    ushort* Bt     = (ushort*)bt_f;
    ushort* xn_bf  = (ushort*)regU;                 // 4096x1024 [dead after in_proj]
    ushort* wi_bf  = (ushort*)(regU + 2097152);     // 4480x1024 [dead after in_proj]
    ushort* ybf    = (ushort*)regU;                 // 4096x2048 [born at ssd_y]
    ushort* wo_bf  = (ushort*)wo_f;

    // 0. prologue (wi cvt, wo'·gw cvt, rmsnorm, ssq=0)
    prologue_kernel<<<dim3(10640), 256, 0, stream>>>(
        x, norm_w, in_proj_w, out_proj_w, gnorm_w, xn_bf, wi_bf, wo_bf, ssq);

    // 1. zxbcdt = xn @ in_proj_w^T -> bf16 (M=4096, N=4384 pad 4480, K=1024)
    //    128x128 tile: 32x35 = 1120 blocks (+XCD swizzle)
    gemm_bf16_kernel<<<dim3(32 * 35), 256, 0, stream>>>(
        xn_bf, DMODEL, 0, wi_bf, DMODEL, 0,
        zxb_bf, DINP, 0, 1, nullptr, nullptr, 32, 35, DINP, DMODEL);

    // 2. conv (main + tail blocks) + dt-softplus+cumsum
    conv_acs_kernel<<<dim3(NROWS + 512 + BB * NCH * NHEADS), 256, 0, stream>>>(
        zxb_bf, conv_w, conv_b, xBC_bf, dt_bias, A_log, dtv, acs);

    // 3. Bt (B^T operand, reads conv'd xBC)
    prep_b_kernel<<<dim3(BB * NCH, 2), 256, 0, stream>>>(xBC_bf, Bt);

    // 4. G2[bc][l][s] = C_l . B_s -> bf16 (batched; M=N=256, K=128; 128x64 tile)
    gemm_bf16_s_kernel<<<dim3(8, 1, BB * NCH), 256, 0, stream>>>(
        xBC_bf + DINNER + DSTATE, CONVD, (long)CHUNK * CONVD,
        xBC_bf + DINNER, CONVD, (long)CHUNK * CONVD,
        G2b, CHUNK, (long)CHUNK * CHUNK, 1, nullptr, nullptr, 2, 4, CHUNK, DSTATE);

    // 5. chunk states (MFMA, in-LDS transpose) -> bf16 state
    chunk_state_mfma_kernel<<<dim3(BB * NCH, NHEADS), 256, 0, stream>>>(
        xBC_bf, Bt, dtv, acs, state);

    // 6. inter-chunk scan (in place, bf16)
    state_scan_kernel<<<dim3(BB * NHEADS * 8192 / 256), 256, 0, stream>>>(state, acs);

    // 7. Y (MFMA diag+off, warp-balanced) + D*xh, silu(z) gate -> ybf + ssq
    ssd_y_mfma_kernel<<<dim3(BB * NCH, NHEADS), 256, 0, stream>>>(
        xBC_bf, G2b, acs, state, zxb_bf, dtv, Dh, ybf, ssq);

    // 8. out = x + rsqrt(ssq/D+eps)*(y @ (gw·Wo)^T)
    //    64x64 tile: 64x16 = 1024 blocks -> 4 resident/CU
    gemm64_kernel<<<dim3(64 * 16), 256, 0, stream>>>(
        ybf, DINNER, wo_bf, DINNER, out, DMODEL, x, ssq, 64, 16, 2048);
}

// Round 13
// 275.743 us; speedup vs baseline: 1.0639x; 1.0177x over previous
//
#include <hip/hip_runtime.h>
#include <hip/hip_bf16.h>

// ---- problem constants ----
#define BB      2
#define LSEQ    2048
#define DMODEL  1024
#define DSTATE  128
#define DCONV   4
#define HEADDIM 64
#define DINNER  2048      // EXP*DMODEL
#define NHEADS  32        // DINNER/HEADDIM
#define CONVD   2304      // DINNER + 2*DSTATE
#define DINP    4384      // 2*DINNER + 2*DSTATE + NHEADS
#define CHUNK   256
#define NCH     8         // LSEQ/CHUNK
#define NROWS   4096      // BB*LSEQ
#define EPSF    1e-5f
#define TPAD    264       // LDS transpose row pitch (ushort)

typedef __attribute__((ext_vector_type(8))) short bf16x8;
typedef __attribute__((ext_vector_type(4))) float f32x4;

#define ASYNC_COPY16(gptr, lptr) \
    __builtin_amdgcn_global_load_lds((const __attribute__((address_space(1))) void*)(gptr), \
                                     (__attribute__((address_space(3))) void*)(lptr), 16, 0, 0)

__device__ __forceinline__ ushort f2bf(float f) {
    __hip_bfloat16 h = __float2bfloat16(f);
    return *(ushort*)&h;
}
__device__ __forceinline__ float bf2f(ushort u) {
    return __uint_as_float(((unsigned)u) << 16);
}
// truncation (toward zero) float->bf16: 1 op, <=2^-8 rel err — hot paths only
__device__ __forceinline__ short tb(float f) { return (short)(__float_as_uint(f) >> 16); }

// XCD-aware bijective pid swizzle: consecutive tiles share one XCD's L2.
// [round-6 proven: gemm1 FETCH 77->35MB, dur 59->52.6us]
__device__ __forceinline__ int xcd_swizzle(int pid, int nwg) {
    return ((nwg & 7) == 0) ? (pid & 7) * (nwg >> 3) + (pid >> 3) : pid;
}

// ============================================================
// Prologue: wi cvt (padded to 4480 rows), wo cvt (pre-scaled by gnorm_w),
// rmsnorm->bf16, ssq zeroing.
// grid: [0,4480) wi | [4480,6528) wo | [6528,10624) rmsnorm | [10624,10640) ssq=0
// ============================================================
__global__ __launch_bounds__(256) void prologue_kernel(
    const float* __restrict__ x, const float* __restrict__ norm_w,
    const float* __restrict__ in_proj_w, const float* __restrict__ out_proj_w,
    const float* __restrict__ gnorm_w,
    ushort* __restrict__ xn_bf, ushort* __restrict__ wi_bf,
    ushort* __restrict__ wo_bf, float* __restrict__ ssq)
{
    int bid = blockIdx.x;
    if (bid < 4480) {                 // wi: 4480x1024 bf16, zero-pad rows >= 4384
        long i4 = ((long)bid * 256 + threadIdx.x) * 4;
        int n = (int)(i4 >> 10);
        long k = i4 & 1023;
        ushort4 o;
        if (n < DINP) {
            float4 v = *(const float4*)(in_proj_w + ((long)n << 10) + k);
            o.x = f2bf(v.x); o.y = f2bf(v.y); o.z = f2bf(v.z); o.w = f2bf(v.w);
        } else { o.x = o.y = o.z = o.w = 0; }
        *(ushort4*)(wi_bf + i4) = o;
    } else if (bid < 6528) {          // wo': 1024x2048 bf16, folded gnorm_w
        long i4 = ((long)(bid - 4480) * 256 + threadIdx.x) * 4;
        int k = (int)(i4 & 2047);
        float4 v = *(const float4*)(out_proj_w + i4);
        float4 g = *(const float4*)(gnorm_w + k);
        ushort4 o;
        o.x = f2bf(v.x * g.x); o.y = f2bf(v.y * g.y);
        o.z = f2bf(v.z * g.z); o.w = f2bf(v.w * g.w);
        *(ushort4*)(wo_bf + i4) = o;
    } else if (bid < 10624) {         // rmsnorm row -> bf16
        int row = bid - 6528;
        const float* xr = x + (long)row * DMODEL;
        float4 v = *(const float4*)(xr + threadIdx.x * 4);
        float ss = v.x*v.x + v.y*v.y + v.z*v.z + v.w*v.w;
        for (int off = 32; off; off >>= 1) ss += __shfl_down(ss, off, 64);
        __shared__ float red[4];
        if ((threadIdx.x & 63) == 0) red[threadIdx.x >> 6] = ss;
        __syncthreads();
        float tot = red[0] + red[1] + red[2] + red[3];
        float scale = rsqrtf(tot / (float)DMODEL + EPSF);
        float4 wv = *(const float4*)(norm_w + threadIdx.x * 4);
        ushort4 o;
        o.x = f2bf(v.x * scale * wv.x); o.y = f2bf(v.y * scale * wv.y);
        o.z = f2bf(v.z * scale * wv.z); o.w = f2bf(v.w * scale * wv.w);
        *(ushort4*)(xn_bf + (long)row * DMODEL + threadIdx.x * 4) = o;
    } else {                          // ssq = 0
        ssq[(bid - 10624) * 256 + threadIdx.x] = 0.f;
    }
}

// ============================================================
// Big bf16 MFMA NT GEMM: 128x128 tile, BK=64, 32 MFMA/K-step.
// [proven: 52.6us gemm1, 0 conflicts, FETCH 35MB w/ swizzle]
// ============================================================
__global__ __launch_bounds__(256, 3) void gemm_bf16_kernel(
    const ushort* __restrict__ A, int lda, long sA,
    const ushort* __restrict__ W, int ldw, long sW,
    void* __restrict__ Cout, int ldc, long sC, int c_bf16,
    const float* __restrict__ resid, const float* __restrict__ rowscale,
    int mtiles, int ntiles, int N, int K)
{
    __shared__ __align__(16) char smem[34816];
    ushort* As = (ushort*)smem;          // 128*64 ushort = 16 KB
    ushort* Bs = As + 128 * 64;          // 128*64 ushort = 16 KB
    ushort* tu = (ushort*)smem;          // epilogue bf16 tile [128][136] = 34 KB
    float*  tf = (float*)smem;           // epilogue fp32 tile [64][132] = 33 KB

    const int t = threadIdx.x;
    const int lane = t & 63;
    const int w = t >> 6;
    const int wm = w & 1, wn = w >> 1;
    const int lm = lane & 15, quad = lane >> 4;

    int pid = xcd_swizzle(blockIdx.x, gridDim.x);
    const int GM = 8;
    int width = GM * ntiles;
    int group = pid / width;
    int first_m = group * GM;
    int gsz = mtiles - first_m; if (gsz > GM) gsz = GM;
    int mt = first_m + (pid % width) % gsz;
    int nt = (pid % width) / gsz;
    const int m0 = mt * 128, n0 = nt * 128;

    A += (long)blockIdx.z * sA;
    W += (long)blockIdx.z * sW;

    const ushort* ga[4]; const ushort* gw[4];
#pragma unroll
    for (int i = 0; i < 4; ++i) {
        int s = i * 256 + t;
        int row = s >> 3;
        int kseg = (s & 7) ^ (row & 7);
        ga[i] = A + (long)(m0 + row) * lda + kseg * 8;
        gw[i] = W + (long)(n0 + row) * ldw + kseg * 8;
    }

    f32x4 acc[4][4];
    f32x4 zero4 = {0.f, 0.f, 0.f, 0.f};
#pragma unroll
    for (int i = 0; i < 4; ++i)
#pragma unroll
        for (int j = 0; j < 4; ++j) acc[i][j] = zero4;

    int arow8[4], arow7[4], brow8[4], brow7[4];
#pragma unroll
    for (int i = 0; i < 4; ++i) {
        int ar = wm * 64 + i * 16 + lm;
        arow8[i] = ar * 8; arow7[i] = ar & 7;
        int br = wn * 64 + i * 16 + lm;
        brow8[i] = br * 8; brow7[i] = br & 7;
    }

    for (int k0 = 0; k0 < K; k0 += 64) {
#pragma unroll
        for (int i = 0; i < 4; ++i) {
            ASYNC_COPY16(ga[i], &As[(i * 256 + w * 64) * 8]);
            ga[i] += 64;
        }
#pragma unroll
        for (int i = 0; i < 4; ++i) {
            ASYNC_COPY16(gw[i], &Bs[(i * 256 + w * 64) * 8]);
            gw[i] += 64;
        }
        __syncthreads();
#pragma unroll
        for (int ks = 0; ks < 2; ++ks) {
            bf16x8 af[4], bfr[4];
#pragma unroll
            for (int i = 0; i < 4; ++i)
                af[i]  = *(const bf16x8*)&As[(arow8[i] + ((ks * 4 + quad) ^ arow7[i])) * 8];
#pragma unroll
            for (int i = 0; i < 4; ++i)
                bfr[i] = *(const bf16x8*)&Bs[(brow8[i] + ((ks * 4 + quad) ^ brow7[i])) * 8];
#pragma unroll
            for (int im = 0; im < 4; ++im)
#pragma unroll
                for (int in = 0; in < 4; ++in)
                    acc[im][in] = __builtin_amdgcn_mfma_f32_16x16x32_bf16(
                        af[im], bfr[in], acc[im][in], 0, 0, 0);
        }
        __syncthreads();
    }

    // ---- epilogue: LDS bounce -> coalesced full-line stores ----
    if (c_bf16) {
        ushort* C = (ushort*)Cout + (long)blockIdx.z * sC;
#pragma unroll
        for (int mi = 0; mi < 4; ++mi)
#pragma unroll
            for (int ni = 0; ni < 4; ++ni) {
                int c = wn * 64 + ni * 16 + lm;
#pragma unroll
                for (int i = 0; i < 4; ++i) {
                    int r = wm * 64 + mi * 16 + quad * 4 + i;
                    tu[r * 136 + c] = f2bf(acc[mi][ni][i]);
                }
            }
        __syncthreads();
        int r = t >> 1, cb = (t & 1) * 64;
        long rowbase = (long)(m0 + r) * ldc + n0 + cb;
#pragma unroll
        for (int q = 0; q < 8; ++q) {
            int gcol = n0 + cb + q * 8;
            if (gcol < N)
                *(bf16x8*)(C + rowbase + q * 8) =
                    *(const bf16x8*)&tu[r * 136 + cb + q * 8];
        }
    } else {
        float* C = (float*)Cout + (long)blockIdx.z * sC;
#pragma unroll
        for (int p = 0; p < 2; ++p) {
            if (wm == p) {
#pragma unroll
                for (int mi = 0; mi < 4; ++mi)
#pragma unroll
                    for (int i = 0; i < 4; ++i) {
                        int r = mi * 16 + quad * 4 + i;
                        float s = 1.f;
                        if (rowscale)
                            s = rsqrtf(rowscale[m0 + p * 64 + r] * (1.f / (float)DINNER) + EPSF);
#pragma unroll
                        for (int ni = 0; ni < 4; ++ni) {
                            int c = wn * 64 + ni * 16 + lm;
                            tf[r * 132 + c] = acc[mi][ni][i] * s;
                        }
                    }
            }
            __syncthreads();
            int r2 = t >> 2, cb = (t & 3) * 32;
            long gbase = (long)(m0 + p * 64 + r2) * ldc + n0 + cb;
#pragma unroll
            for (int q = 0; q < 8; ++q) {
                float4 v = *(const float4*)&tf[r2 * 132 + cb + q * 4];
                if (resid) {
                    float4 rv = *(const float4*)(resid + gbase + q * 4);
                    v.x += rv.x; v.y += rv.y; v.z += rv.z; v.w += rv.w;
                }
                *(float4*)(C + gbase + q * 4) = v;
            }
            __syncthreads();
        }
    }
}

// ============================================================
// Small bf16 MFMA NT GEMM: 128x64 tile, 16 MFMA/K-step — used for
// gemm4 (bf16-out batched tiny GEMM).
// ============================================================
__global__ __launch_bounds__(256, 4) void gemm_bf16_s_kernel(
    const ushort* __restrict__ A, int lda, long sA,
    const ushort* __restrict__ W, int ldw, long sW,
    void* __restrict__ Cout, int ldc, long sC, int c_bf16,
    const float* __restrict__ resid, const float* __restrict__ rowscale,
    int mtiles, int ntiles, int N, int K)
{
    __shared__ __align__(16) char smem[24576];
    ushort* As = (ushort*)smem;          // 128*64 ushort = 16 KB
    ushort* Bs = As + 128 * 64;          //  64*64 ushort =  8 KB
    ushort* tu = (ushort*)smem;          // epilogue bf16 tile [128][72]
    float*  tf = (float*)smem;           // epilogue fp32 tile [64][68]

    const int t = threadIdx.x;
    const int lane = t & 63;
    const int w = t >> 6;
    const int wm = w & 1, wn = w >> 1;
    const int lm = lane & 15, quad = lane >> 4;

    int pid = xcd_swizzle(blockIdx.x, gridDim.x);
    const int GM = 8;
    int width = GM * ntiles;
    int group = pid / width;
    int first_m = group * GM;
    int gsz = mtiles - first_m; if (gsz > GM) gsz = GM;
    int mt = first_m + (pid % width) % gsz;
    int nt = (pid % width) / gsz;
    const int m0 = mt * 128, n0 = nt * 64;

    A += (long)blockIdx.z * sA;
    W += (long)blockIdx.z * sW;

    const ushort* ga[4]; const ushort* gw[2];
#pragma unroll
    for (int i = 0; i < 4; ++i) {
        int s = i * 256 + t;
        int row = s >> 3;
        int kseg = (s & 7) ^ (row & 7);
        ga[i] = A + (long)(m0 + row) * lda + kseg * 8;
    }
#pragma unroll
    for (int i = 0; i < 2; ++i) {
        int s = i * 256 + t;
        int row = s >> 3;
        int kseg = (s & 7) ^ (row & 7);
        gw[i] = W + (long)(n0 + row) * ldw + kseg * 8;
    }

    f32x4 acc[4][2];
    f32x4 zero4 = {0.f, 0.f, 0.f, 0.f};
#pragma unroll
    for (int i = 0; i < 4; ++i) { acc[i][0] = zero4; acc[i][1] = zero4; }

    int arow8[4], arow7[4], brow8[2], brow7[2];
#pragma unroll
    for (int i = 0; i < 4; ++i) {
        int ar = wm * 64 + i * 16 + lm;
        arow8[i] = ar * 8; arow7[i] = ar & 7;
    }
#pragma unroll
    for (int i = 0; i < 2; ++i) {
        int br = wn * 32 + i * 16 + lm;
        brow8[i] = br * 8; brow7[i] = br & 7;
    }

    for (int k0 = 0; k0 < K; k0 += 64) {
#pragma unroll
        for (int i = 0; i < 4; ++i) {
            ASYNC_COPY16(ga[i], &As[(i * 256 + w * 64) * 8]);
            ga[i] += 64;
        }
#pragma unroll
        for (int i = 0; i < 2; ++i) {
            ASYNC_COPY16(gw[i], &Bs[(i * 256 + w * 64) * 8]);
            gw[i] += 64;
        }
        __syncthreads();
#pragma unroll
        for (int ks = 0; ks < 2; ++ks) {
            bf16x8 af[4], bfr[2];
#pragma unroll
            for (int i = 0; i < 4; ++i)
                af[i]  = *(const bf16x8*)&As[(arow8[i] + ((ks * 4 + quad) ^ arow7[i])) * 8];
#pragma unroll
            for (int i = 0; i < 2; ++i)
                bfr[i] = *(const bf16x8*)&Bs[(brow8[i] + ((ks * 4 + quad) ^ brow7[i])) * 8];
#pragma unroll
            for (int im = 0; im < 4; ++im)
#pragma unroll
                for (int in = 0; in < 2; ++in)
                    acc[im][in] = __builtin_amdgcn_mfma_f32_16x16x32_bf16(
                        af[im], bfr[in], acc[im][in], 0, 0, 0);
        }
        __syncthreads();
    }

    // ---- epilogue: LDS bounce -> coalesced full-line stores ----
    if (c_bf16) {
        ushort* C = (ushort*)Cout + (long)blockIdx.z * sC;
#pragma unroll
        for (int mi = 0; mi < 4; ++mi)
#pragma unroll
            for (int ni = 0; ni < 2; ++ni) {
                int c = wn * 32 + ni * 16 + lm;
#pragma unroll
                for (int i = 0; i < 4; ++i) {
                    int r = wm * 64 + mi * 16 + quad * 4 + i;
                    tu[r * 72 + c] = f2bf(acc[mi][ni][i]);
                }
            }
        __syncthreads();
        int r = t >> 1, cb = (t & 1) * 32;
        long rowbase = (long)(m0 + r) * ldc + n0 + cb;
#pragma unroll
        for (int q = 0; q < 4; ++q) {
            int gcol = n0 + cb + q * 8;
            if (gcol < N)
                *(bf16x8*)(C + rowbase + q * 8) =
                    *(const bf16x8*)&tu[r * 72 + cb + q * 8];
        }
    } else {
        float* C = (float*)Cout + (long)blockIdx.z * sC;
#pragma unroll
        for (int p = 0; p < 2; ++p) {
            if (wm == p) {
#pragma unroll
                for (int mi = 0; mi < 4; ++mi)
#pragma unroll
                    for (int i = 0; i < 4; ++i) {
                        int r = mi * 16 + quad * 4 + i;
                        float s = 1.f;
                        if (rowscale)
                            s = rsqrtf(rowscale[m0 + p * 64 + r] * (1.f / (float)DINNER) + EPSF);
#pragma unroll
                        for (int ni = 0; ni < 2; ++ni) {
                            int c = wn * 32 + ni * 16 + lm;
                            tf[r * 68 + c] = acc[mi][ni][i] * s;
                        }
                    }
            }
            __syncthreads();
            int r2 = t >> 2, cb = (t & 3) * 16;
            long gbase = (long)(m0 + p * 64 + r2) * ldc + n0 + cb;
#pragma unroll
            for (int q = 0; q < 4; ++q) {
                float4 v = *(const float4*)&tf[r2 * 68 + cb + q * 4];
                if (resid) {
                    float4 rv = *(const float4*)(resid + gbase + q * 4);
                    v.x += rv.x; v.y += rv.y; v.z += rv.z; v.w += rv.w;
                }
                *(float4*)(C + gbase + q * 4) = v;
            }
            __syncthreads();
        }
    }
}

// ============================================================
// 64x64-tile bf16 MFMA NT GEMM for gemm8 (latency-bound K=2048):
// 1024 blocks -> 4 resident/CU. [round-10 proven: gemm8 out of top-5]
// ============================================================
__global__ __launch_bounds__(256, 4) void gemm64_kernel(
    const ushort* __restrict__ A, int lda,
    const ushort* __restrict__ W, int ldw,
    float* __restrict__ Cout, int ldc,
    const float* __restrict__ resid, const float* __restrict__ rowscale,
    int mtiles, int ntiles, int K)
{
    __shared__ __align__(16) char smem[17408];
    ushort* As = (ushort*)smem;          // 64*64 ushort = 8 KB
    ushort* Bs = As + 64 * 64;           // 8 KB
    float*  tf = (float*)smem;           // epilogue fp32 tile [64][68] = 17408 B

    const int t = threadIdx.x;
    const int lane = t & 63;
    const int w = t >> 6;
    const int wm = w & 1, wn = w >> 1;
    const int lm = lane & 15, quad = lane >> 4;

    int pid = xcd_swizzle(blockIdx.x, gridDim.x);
    const int GM = 8;
    int width = GM * ntiles;
    int group = pid / width;
    int first_m = group * GM;
    int gsz = mtiles - first_m; if (gsz > GM) gsz = GM;
    int mt = first_m + (pid % width) % gsz;
    int nt = (pid % width) / gsz;
    const int m0 = mt * 64, n0 = nt * 64;

    const ushort* ga[2]; const ushort* gw[2];
#pragma unroll
    for (int i = 0; i < 2; ++i) {
        int s = i * 256 + t;
        int row = s >> 3;
        int kseg = (s & 7) ^ (row & 7);
        ga[i] = A + (long)(m0 + row) * lda + kseg * 8;
        gw[i] = W + (long)(n0 + row) * ldw + kseg * 8;
    }

    f32x4 acc[2][2];
    f32x4 zero4 = {0.f, 0.f, 0.f, 0.f};
    acc[0][0] = zero4; acc[0][1] = zero4;
    acc[1][0] = zero4; acc[1][1] = zero4;

    int arow8[2], arow7[2], brow8[2], brow7[2];
#pragma unroll
    for (int i = 0; i < 2; ++i) {
        int ar = wm * 32 + i * 16 + lm;
        arow8[i] = ar * 8; arow7[i] = ar & 7;
        int br = wn * 32 + i * 16 + lm;
        brow8[i] = br * 8; brow7[i] = br & 7;
    }

    for (int k0 = 0; k0 < K; k0 += 64) {
#pragma unroll
        for (int i = 0; i < 2; ++i) {
            ASYNC_COPY16(ga[i], &As[(i * 256 + w * 64) * 8]);
            ga[i] += 64;
            ASYNC_COPY16(gw[i], &Bs[(i * 256 + w * 64) * 8]);
            gw[i] += 64;
        }
        __syncthreads();
#pragma unroll
        for (int ks = 0; ks < 2; ++ks) {
            bf16x8 af[2], bfr[2];
#pragma unroll
            for (int i = 0; i < 2; ++i) {
                af[i]  = *(const bf16x8*)&As[(arow8[i] + ((ks * 4 + quad) ^ arow7[i])) * 8];
                bfr[i] = *(const bf16x8*)&Bs[(brow8[i] + ((ks * 4 + quad) ^ brow7[i])) * 8];
            }
#pragma unroll
            for (int im = 0; im < 2; ++im)
#pragma unroll
                for (int in = 0; in < 2; ++in)
                    acc[im][in] = __builtin_amdgcn_mfma_f32_16x16x32_bf16(
                        af[im], bfr[in], acc[im][in], 0, 0, 0);
        }
        __syncthreads();
    }

    // ---- epilogue: rowscale + resid, LDS bounce -> coalesced fp32 stores ----
#pragma unroll
    for (int mi = 0; mi < 2; ++mi)
#pragma unroll
        for (int i = 0; i < 4; ++i) {
            int r = wm * 32 + mi * 16 + quad * 4 + i;
            float s = rsqrtf(rowscale[m0 + r] * (1.f / (float)DINNER) + EPSF);
#pragma unroll
            for (int ni = 0; ni < 2; ++ni) {
                int c = wn * 32 + ni * 16 + lm;
                tf[r * 68 + c] = acc[mi][ni][i] * s;
            }
        }
    __syncthreads();
    int r2 = t >> 2, cb = (t & 3) * 16;
    long gbase = (long)(m0 + r2) * ldc + n0 + cb;
#pragma unroll
    for (int q = 0; q < 4; ++q) {
        float4 v = *(const float4*)&tf[r2 * 68 + cb + q * 4];
        float4 rv = *(const float4*)(resid + gbase + q * 4);
        v.x += rv.x; v.y += rv.y; v.z += rv.z; v.w += rv.w;
        *(float4*)(Cout + gbase + q * 4) = v;
    }
}

// ============================================================
// Merged conv+SiLU + dt-softplus/cumsum + fused Bt transpose.
// Main conv: per-row layout (ch 0..2047, 8 ch/thread).
// Tail: ch 2048..2303, 8 rows per block; B channels (2048..2175)
// additionally bounced through LDS and written transposed to
// Bt[bc][n][l] — eliminates the separate prep_b launch.
// grid: [0,4096) conv main | [4096,4608) conv tail | [4608,5120) acs
// ============================================================
__device__ __forceinline__ void conv8_compute(
    const ushort* __restrict__ zx, const float* __restrict__ cw,
    const float* __restrict__ cb, int row, int l, int c, ushort* o)
{
    float4 cwv[8];
#pragma unroll
    for (int j = 0; j < 8; ++j) cwv[j] = *(const float4*)(cw + (c + j) * 4);
    float acc[8];
    {
        float4 b0 = *(const float4*)(cb + c);
        float4 b1 = *(const float4*)(cb + c + 4);
        acc[0] = b0.x; acc[1] = b0.y; acc[2] = b0.z; acc[3] = b0.w;
        acc[4] = b1.x; acc[5] = b1.y; acc[6] = b1.z; acc[7] = b1.w;
    }
#pragma unroll
    for (int k = 0; k < DCONV; ++k) {
        int ls = l + k - (DCONV - 1);
        if (ls >= 0) {
            const ushort* zr = zx + (long)(row + k - (DCONV - 1)) * DINP + DINNER + c;
            ushort4 a = *(const ushort4*)zr;
            ushort4 b = *(const ushort4*)(zr + 4);
            acc[0] += bf2f(a.x) * ((const float*)&cwv[0])[k];
            acc[1] += bf2f(a.y) * ((const float*)&cwv[1])[k];
            acc[2] += bf2f(a.z) * ((const float*)&cwv[2])[k];
            acc[3] += bf2f(a.w) * ((const float*)&cwv[3])[k];
            acc[4] += bf2f(b.x) * ((const float*)&cwv[4])[k];
            acc[5] += bf2f(b.y) * ((const float*)&cwv[5])[k];
            acc[6] += bf2f(b.z) * ((const float*)&cwv[6])[k];
            acc[7] += bf2f(b.w) * ((const float*)&cwv[7])[k];
        }
    }
#pragma unroll
    for (int j = 0; j < 8; ++j)
        o[j] = f2bf(acc[j] / (1.f + __expf(-acc[j])));
}

__global__ __launch_bounds__(256) void conv_acs_kernel(
    const ushort* __restrict__ zx, const float* __restrict__ cw,
    const float* __restrict__ cb, ushort* __restrict__ xBC_bf,
    const float* __restrict__ dt_bias, const float* __restrict__ A_log,
    float* __restrict__ dtv, float* __restrict__ Acs,
    ushort* __restrict__ Bt)
{
    int bid = blockIdx.x;
    int t = threadIdx.x;
    if (bid < NROWS) {
        // ---- conv main: ch 0..2047, one row per block ----
        int row = bid;
        int l = row & (LSEQ - 1);
        int c = t * 8;
        ushort o[8];
        conv8_compute(zx, cw, cb, row, l, c, o);
        ushort* dst = xBC_bf + (long)row * CONVD + c;
        *(ushort4*)dst = *(ushort4*)&o[0];
        *(ushort4*)(dst + 4) = *(ushort4*)&o[4];
    } else if (bid < NROWS + 512) {
        // ---- conv tail: ch 2048..2303, 8 rows per block; fused Bt ----
        __shared__ ushort tBt[8][132];   // [l-sub][n] (+4 pad)
        int bidx = bid - NROWS;
        int row0b = bidx * 8;            // 8 rows, all within one chunk
        int rl = t >> 5;                 // 0..7
        int cg = t & 31;                 // 0..31
        int row = row0b + rl;
        int c = 2048 + cg * 8;
        int l = row & (LSEQ - 1);
        ushort o[8];
        conv8_compute(zx, cw, cb, row, l, c, o);
        ushort* dst = xBC_bf + (long)row * CONVD + c;
        *(ushort4*)dst = *(ushort4*)&o[0];
        *(ushort4*)(dst + 4) = *(ushort4*)&o[4];
        if (cg < 16) {                   // B channels: n = cg*8..cg*8+7
            *(ushort4*)&tBt[rl][cg * 8] = *(ushort4*)&o[0];
            *(ushort4*)&tBt[rl][cg * 8 + 4] = *(ushort4*)&o[4];
        }
        __syncthreads();
        if (t < 128) {                   // write Bt[bc][n][lseg..lseg+7]
            int n = t;
            int bc = row0b >> 8;
            int lseg = row0b & (CHUNK - 1);
            ushort u[8];
#pragma unroll
            for (int j = 0; j < 8; ++j) u[j] = tBt[j][n];
            ushort* bp = Bt + ((long)bc * DSTATE + n) * CHUNK + lseg;
            *(ushort4*)bp = *(ushort4*)&u[0];
            *(ushort4*)(bp + 4) = *(ushort4*)&u[4];
        }
    } else {
        // ---- dt softplus + per-chunk cumsum ----
        __shared__ float buf[2 * CHUNK];
        int idx = bid - (NROWS + 512);
        int bc = idx >> 5, h = idx & 31;
        int l = t;
        int row = bc * CHUNK + l;
        float v = bf2f(zx[(long)row * DINP + (DINP - NHEADS) + h]) + dt_bias[h];
        float d = (v > 20.f) ? v : log1pf(__expf(v));
        dtv[row * NHEADS + h] = d;
        float a = -d * __expf(A_log[h]);
        buf[l] = a; __syncthreads();
        int src = 0;
        for (int off = 1; off < CHUNK; off <<= 1) {
            float vv = buf[src * CHUNK + l];
            if (l >= off) vv += buf[src * CHUNK + l - off];
            buf[(src ^ 1) * CHUNK + l] = vv;
            __syncthreads();
            src ^= 1;
        }
        Acs[(bc * NHEADS + h) * CHUNK + l] = buf[src * CHUNK + l];
    }
}

// ============================================================
// Chunk state via MFMA with in-LDS X transpose:
//   S_t[p][n] = sum_l exp(T-acs_l)*dt_l*X[l,p] * Bt[n][l]  -> bf16
// ============================================================
__global__ __launch_bounds__(256) void chunk_state_mfma_kernel(
    const ushort* __restrict__ xBC_bf, const ushort* __restrict__ Bt,
    const float* __restrict__ dtv, const float* __restrict__ acs,
    ushort* __restrict__ state)
{
    int bc = blockIdx.x, h = blockIdx.y;
    int t = threadIdx.x, lane = t & 63, w = t >> 6;
    int lm = lane & 15, quad = lane >> 4;
    int row0 = bc * CHUNK;
    __shared__ ushort xt[64 * TPAD];
    __shared__ float cl[CHUNK];
    {
        float a = acs[(bc * NHEADS + h) * CHUNK + t];
        float T = acs[(bc * NHEADS + h) * CHUNK + CHUNK - 1];
        cl[t] = __expf(T - a) * dtv[(row0 + t) * NHEADS + h];
    }
    __syncthreads();
    for (int iter = 0; iter < 8; ++iter) {
        int l = iter * 32 + (t >> 3);
        int cc = (t & 7) * 8;
        ushort u[8];
        *(ushort4*)&u[0] = *(const ushort4*)(xBC_bf + (long)(row0 + l) * CONVD + h * HEADDIM + cc);
        *(ushort4*)&u[4] = *(const ushort4*)(xBC_bf + (long)(row0 + l) * CONVD + h * HEADDIM + cc + 4);
        float sc = cl[l];
#pragma unroll
        for (int j = 0; j < 8; ++j)
            xt[(cc + j) * TPAD + l] = (ushort)tb(bf2f(u[j]) * sc);
    }
    __syncthreads();

    const ushort* Bb = Bt + (long)bc * DSTATE * CHUNK;
    f32x4 acc[4][2];
    f32x4 zero4 = {0.f, 0.f, 0.f, 0.f};
#pragma unroll
    for (int i = 0; i < 4; ++i) { acc[i][0] = zero4; acc[i][1] = zero4; }

    for (int kt = 0; kt < 8; ++kt) {
        int k = kt * 32 + quad * 8;
        bf16x8 af[4], bfr[2];
#pragma unroll
        for (int mi = 0; mi < 4; ++mi)
            af[mi] = *(const bf16x8*)&xt[(mi * 16 + lm) * TPAD + k];
#pragma unroll
        for (int nj = 0; nj < 2; ++nj)
            bfr[nj] = *(const bf16x8*)(Bb + (long)(w * 32 + nj * 16 + lm) * CHUNK + k);
#pragma unroll
        for (int mi = 0; mi < 4; ++mi)
#pragma unroll
            for (int nj = 0; nj < 2; ++nj)
                acc[mi][nj] = __builtin_amdgcn_mfma_f32_16x16x32_bf16(
                    af[mi], bfr[nj], acc[mi][nj], 0, 0, 0);
    }
    ushort* sp = state + (long)(bc * NHEADS + h) * (DSTATE * HEADDIM);
#pragma unroll
    for (int mi = 0; mi < 4; ++mi)
#pragma unroll
        for (int nj = 0; nj < 2; ++nj) {
            int n = w * 32 + nj * 16 + lm;
#pragma unroll
            for (int i = 0; i < 4; ++i) {
                int p = mi * 16 + quad * 4 + i;
                sp[p * DSTATE + n] = f2bf(acc[mi][nj][i]);
            }
        }
}

// ============================================================
// Inter-chunk scan (in place on bf16 states, fp32 accumulator)
// ============================================================
__global__ __launch_bounds__(256) void state_scan_kernel(
    ushort* __restrict__ state, const float* __restrict__ Acs)
{
    long flat = (long)blockIdx.x * 256 + threadIdx.x;
    int e = (int)(flat & 8191);
    int bh = (int)(flat >> 13);
    int b = bh >> 5, h = bh & 31;
    float S = 0.f;
    for (int c = 0; c < NCH; ++c) {
        int bc = b * NCH + c;
        long idx = ((long)(bc * NHEADS + h)) * 8192 + e;
        float T = Acs[(bc * NHEADS + h) * CHUNK + CHUNK - 1];
        float tmp = bf2f(state[idx]);
        state[idx] = f2bf(S);
        S = S * __expf(T) + tmp;
    }
}

// ============================================================
// SSD Y via MFMA (in-LDS Xdt transpose): Y = P@Xdt + (C*eAl)@S^T,
// then +D*xh, silu(z) gate, bf16 store + per-row ssq atomics.
// Warp-balanced causal mapping: warp w owns rows {mi*64 + w*16 + r}
// -> phase-A critical path 20 MFMA-groups (16/16/20/20 per warp).
// [round-9/10/12 proven config]
// ============================================================
__global__ __launch_bounds__(256) void ssd_y_mfma_kernel(
    const ushort* __restrict__ xBC_bf, const ushort* __restrict__ G2b,
    const float* __restrict__ acs, const ushort* __restrict__ state,
    const ushort* __restrict__ zxb, const float* __restrict__ dtv,
    const float* __restrict__ Dh, ushort* __restrict__ ybf,
    float* __restrict__ ssq)
{
    int bc = blockIdx.x, h = blockIdx.y;
    int t = threadIdx.x, lane = t & 63, w = t >> 6;
    int lm = lane & 15, quad = lane >> 4;
    int row0 = bc * CHUNK;
    __shared__ ushort xt[64 * TPAD];
    __shared__ float acs_s[CHUNK];
    __shared__ float dl[CHUNK];
    acs_s[t] = acs[(bc * NHEADS + h) * CHUNK + t];
    dl[t] = dtv[(row0 + t) * NHEADS + h];
    __syncthreads();
    // transpose X chunk (dt-scaled) into LDS [p][l]
    for (int iter = 0; iter < 8; ++iter) {
        int l = iter * 32 + (t >> 3);
        int cc = (t & 7) * 8;
        ushort u[8];
        *(ushort4*)&u[0] = *(const ushort4*)(xBC_bf + (long)(row0 + l) * CONVD + h * HEADDIM + cc);
        *(ushort4*)&u[4] = *(const ushort4*)(xBC_bf + (long)(row0 + l) * CONVD + h * HEADDIM + cc + 4);
        float sd = dl[l];
#pragma unroll
        for (int j = 0; j < 8; ++j)
            xt[(cc + j) * TPAD + l] = (ushort)tb(bf2f(u[j]) * sd);
    }
    __syncthreads();

    // balanced row base per mi: rows mi*64 + w*16 .. +15
    int rb[4];
    float acs_l[4], eAl[4];
#pragma unroll
    for (int mi = 0; mi < 4; ++mi) {
        rb[mi] = mi * 64 + w * 16;
        acs_l[mi] = acs_s[rb[mi] + lm];
        eAl[mi] = __expf(acs_l[mi]);
    }
    f32x4 acc[4][4];
    f32x4 zero4 = {0.f, 0.f, 0.f, 0.f};
#pragma unroll
    for (int i = 0; i < 4; ++i)
#pragma unroll
        for (int j = 0; j < 4; ++j) acc[i][j] = zero4;

    const ushort* g2 = G2b + (long)bc * (CHUNK * CHUNK);

    // ---- phase A: diagonal (causal), factored exps ----
    int ksmax = (192 + w * 16 + 15) >> 5;   // max over mi of (rb[mi]+15)/32
    for (int ks = 0; ks <= ksmax; ++ks) {
        int sq = ks * 32 + quad * 8;
        bf16x8 bfr[4];
#pragma unroll
        for (int ni = 0; ni < 4; ++ni)
            bfr[ni] = *(const bf16x8*)&xt[(ni * 16 + lm) * TPAD + sq];
        float base = acs_s[sq];
        float e8[8];
        e8[0] = 1.f;
#pragma unroll
        for (int j = 1; j < 8; ++j)
            e8[j] = __expf(fminf(base - acs_s[sq + j], 80.f));
#pragma unroll
        for (int mi = 0; mi < 4; ++mi) {
            int lmin = rb[mi];
            if (ks * 32 > lmin + 15) continue;
            int lv = lmin + lm;
            float em = __expf(fminf(acs_l[mi] - base, 0.f));
            bf16x8 g8 = *(const bf16x8*)(g2 + (long)lv * CHUNK + sq);
            bf16x8 af;
#pragma unroll
            for (int j = 0; j < 8; ++j) {
                float v = bf2f((ushort)g8[j]) * (em * e8[j]);
                af[j] = (sq + j > lv) ? (short)0 : tb(v);
            }
#pragma unroll
            for (int ni = 0; ni < 4; ++ni)
                acc[mi][ni] = __builtin_amdgcn_mfma_f32_16x16x32_bf16(
                    af, bfr[ni], acc[mi][ni], 0, 0, 0);
        }
    }

    // ---- phase B: off-diagonal (C*eAl @ S^T), bf16 state loads ----
    const ushort* sp = state + (long)(bc * NHEADS + h) * (DSTATE * HEADDIM);
    const ushort* Cb = xBC_bf + (long)row0 * CONVD + DINNER + DSTATE;
    for (int kt = 0; kt < 4; ++kt) {
        int n0 = kt * 32 + quad * 8;
        bf16x8 bfr[4];
#pragma unroll
        for (int ni = 0; ni < 4; ++ni)
            bfr[ni] = *(const bf16x8*)(sp + (long)(ni * 16 + lm) * DSTATE + n0);
#pragma unroll
        for (int mi = 0; mi < 4; ++mi) {
            int lv = rb[mi] + lm;
            bf16x8 cu = *(const bf16x8*)(Cb + (long)lv * CONVD + n0);
            bf16x8 ce;
            float e = eAl[mi];
#pragma unroll
            for (int j = 0; j < 8; ++j) ce[j] = tb(bf2f((ushort)cu[j]) * e);
#pragma unroll
            for (int ni = 0; ni < 4; ++ni)
                acc[mi][ni] = __builtin_amdgcn_mfma_f32_16x16x32_bf16(
                    ce, bfr[ni], acc[mi][ni], 0, 0, 0);
        }
    }

    // ---- epilogue: +D*xh, silu(z) gate, bf16 store + ssq ----
    float Dv = Dh[h];
#pragma unroll
    for (int mi = 0; mi < 4; ++mi)
#pragma unroll
        for (int i = 0; i < 4; ++i) {
            int l = rb[mi] + quad * 4 + i;
            long row = row0 + l;
            float ps = 0.f;
#pragma unroll
            for (int ni = 0; ni < 4; ++ni) {
                int p = ni * 16 + lm;
                float xh = bf2f(xBC_bf[row * CONVD + h * HEADDIM + p]);
                float z = bf2f(zxb[row * DINP + h * HEADDIM + p]);
                float o = (acc[mi][ni][i] + Dv * xh) * (z / (1.f + __expf(-z)));
                ps += o * o;
                ybf[row * DINNER + h * HEADDIM + p] = f2bf(o);
            }
#pragma unroll
            for (int m = 1; m < 16; m <<= 1) ps += __shfl_xor(ps, m, 64);
            if (lm == 0) atomicAdd(&ssq[row], ps);
        }
}

// ============================================================
// launch
// ============================================================
extern "C" void kernel_launch(void* const* d_in, const int* in_sizes, int n_in,
                              void* d_out, int out_size, void* d_ws, size_t ws_size,
                              hipStream_t stream)
{
    (void)in_sizes; (void)n_in; (void)out_size; (void)ws_size;
    const float* x          = (const float*)d_in[0];
    const float* norm_w     = (const float*)d_in[1];
    const float* in_proj_w  = (const float*)d_in[2];
    const float* conv_w     = (const float*)d_in[3];
    const float* conv_b     = (const float*)d_in[4];
    const float* dt_bias    = (const float*)d_in[5];
    const float* A_log      = (const float*)d_in[6];
    const float* Dh         = (const float*)d_in[7];
    const float* gnorm_w    = (const float*)d_in[8];
    const float* out_proj_w = (const float*)d_in[9];
    float* out = (float*)d_out;
    float* ws = (float*)d_ws;

    // workspace layout (float slots); total ~90 MB
    float* zxb_f   = ws;                       //  8,978,432 (bf16 4096x4384)
    float* xbc_f   = zxb_f   + 8978432;        //  4,718,592 (bf16 4096x2304)
    float* dtv     = xbc_f   + 4718592;        //    131,072
    float* acs     = dtv     + 131072;         //    131,072
    float* g2_f    = acs     + 131072;         //    524,288 (bf16 [bc][l][s])
    float* state_f = g2_f    + 524288;         //  2,097,152 (bf16 [bc][h][p][n])
    float* bt_f    = state_f + 2097152;        //    262,144 (bf16 [bc][n][l])
    float* regU    = bt_f    + 262144;         //  4,390,912 (xn_bf+wi_bf, later ybf)
    float* wo_f    = regU    + 4390912;        //  1,048,576 (wo_bf)
    float* ssq     = wo_f    + 1048576;        //      4,096

    ushort* zxb_bf = (ushort*)zxb_f;
    ushort* xBC_bf = (ushort*)xbc_f;
    ushort* G2b    = (ushort*)g2_f;
    ushort* state  = (ushort*)state_f;
    ushort* Bt     = (ushort*)bt_f;
    ushort* xn_bf  = (ushort*)regU;                 // 4096x1024 [dead after in_proj]
    ushort* wi_bf  = (ushort*)(regU + 2097152);     // 4480x1024 [dead after in_proj]
    ushort* ybf    = (ushort*)regU;                 // 4096x2048 [born at ssd_y]
    ushort* wo_bf  = (ushort*)wo_f;

    // 0. prologue (wi cvt, wo'·gw cvt, rmsnorm, ssq=0)
    prologue_kernel<<<dim3(10640), 256, 0, stream>>>(
        x, norm_w, in_proj_w, out_proj_w, gnorm_w, xn_bf, wi_bf, wo_bf, ssq);

    // 1. zxbcdt = xn @ in_proj_w^T -> bf16 (M=4096, N=4384 pad 4480, K=1024)
    //    128x128 tile: 32x35 = 1120 blocks (+XCD swizzle)
    gemm_bf16_kernel<<<dim3(32 * 35), 256, 0, stream>>>(
        xn_bf, DMODEL, 0, wi_bf, DMODEL, 0,
        zxb_bf, DINP, 0, 1, nullptr, nullptr, 32, 35, DINP, DMODEL);

    // 2. conv (main + tail w/ fused Bt transpose) + dt-softplus+cumsum
    conv_acs_kernel<<<dim3(NROWS + 512 + BB * NCH * NHEADS), 256, 0, stream>>>(
        zxb_bf, conv_w, conv_b, xBC_bf, dt_bias, A_log, dtv, acs, Bt);

    // 3. G2[bc][l][s] = C_l . B_s -> bf16 (batched; M=N=256, K=128; 128x64 tile)
    gemm_bf16_s_kernel<<<dim3(8, 1, BB * NCH), 256, 0, stream>>>(
        xBC_bf + DINNER + DSTATE, CONVD, (long)CHUNK * CONVD,
        xBC_bf + DINNER, CONVD, (long)CHUNK * CONVD,
        G2b, CHUNK, (long)CHUNK * CHUNK, 1, nullptr, nullptr, 2, 4, CHUNK, DSTATE);

    // 4. chunk states (MFMA, in-LDS transpose) -> bf16 state
    chunk_state_mfma_kernel<<<dim3(BB * NCH, NHEADS), 256, 0, stream>>>(
        xBC_bf, Bt, dtv, acs, state);

    // 5. inter-chunk scan (in place, bf16)
    state_scan_kernel<<<dim3(BB * NHEADS * 8192 / 256), 256, 0, stream>>>(state, acs);

    // 6. Y (MFMA diag+off, warp-balanced) + D*xh, silu(z) gate -> ybf + ssq
    ssd_y_mfma_kernel<<<dim3(BB * NCH, NHEADS), 256, 0, stream>>>(
        xBC_bf, G2b, acs, state, zxb_bf, dtv, Dh, ybf, ssq);

    // 7. out = x + rsqrt(ssq/D+eps)*(y @ (gw·Wo)^T)
    //    64x64 tile: 64x16 = 1024 blocks -> 4 resident/CU
    gemm64_kernel<<<dim3(64 * 16), 256, 0, stream>>>(
        ybf, DINNER, wo_bf, DINNER, out, DMODEL, x, ssq, 64, 16, 2048);
}